// Round 10
// baseline (708.261 us; speedup 1.0000x reference)
//
#include <hip/hip_runtime.h>
#include <hip/hip_bf16.h>
#include <math.h>

// Problem constants
#define B_SZ 1024
#define T_SZ 128
#define H_SZ 256
#define DIN  128
#define G4   1024   // 4*H
#define FINW 672

using bf16   = __hip_bfloat16;
using short8 = __attribute__((ext_vector_type(8))) short;  // 8 bf16 (4 VGPRs)
using short4v = __attribute__((ext_vector_type(4))) short;
using f32x4  = __attribute__((ext_vector_type(4))) float;

__device__ __forceinline__ float bf2f(bf16 x) { return __bfloat162float(x); }
__device__ __forceinline__ bf16  f2bf(float x) { return __float2bfloat16(x); }
__device__ __forceinline__ float sigm(float x) { return 1.0f / (1.0f + __expf(-x)); }
__device__ __forceinline__ float ftanh(float x) { return 2.0f / (1.0f + __expf(-2.0f * x)) - 1.0f; }
__device__ __forceinline__ float bfraw2f(unsigned short r) {
  unsigned u = ((unsigned)r) << 16;
  return *reinterpret_cast<float*>(&u);
}

struct Ptrs { const void* p[33]; };

#define NSEG 30
__device__ __host__ constexpr int kSegOffArr(int i) {
  constexpr int off[NSEG + 1] = {
      0,       32768,   672768,  736768,  768768,  784768,  915840,
      1177984, 1179008, 1180032, 1245568, 1245824, 1278592, 1278848,
      1344384, 1409920, 1475456, 1819520, 1820032, 1820544, 1821056,
      1821568, 1822080, 1953152, 1953408, 1953664, 1953920, 1954176,
      1954432, 1970816, 1970880};
  return off[i];
}
#define ARENA_TOTAL 1970880
// transposed-weight extension region: WT[k][n] layouts for k_finmlp
#define TR_BASE   1970880
#define TR_WthT   0        // 65536  (W_tpa_h^T, src p[17])
#define TR_WtcT   65536    // 65536  (W_tpa_c^T, src p[18])
#define TR_WltT   131072   // 65536  (W_ltd^T,   src p[12])
#define TR_WcvT   196608   // 32768  (W_conv^T,  src p[14])
#define TR_TOTAL  229376
#define ARENA_TOTAL2 (ARENA_TOTAL + TR_TOTAL)

// ---------------------------------------------------------------------------
// 0) Convert float inputs to bf16 arena + transposed weight copies + hs
//    poison (fused; no separate memset launch).
// ---------------------------------------------------------------------------
__global__ __launch_bounds__(256) void k_convert(Ptrs pk, bf16* __restrict__ dst,
                                                 uint4* __restrict__ hsp) {
  bool isf32 = ((((const unsigned*)pk.p[24])[0] & 0xFFFFu) == 0u);
  int stride = gridDim.x * blockDim.x;
  int gtid = blockIdx.x * blockDim.x + threadIdx.x;
  for (int i = gtid; i < ARENA_TOTAL; i += stride) {
    int s = 0, base = 0;
#pragma unroll
    for (int j = 1; j < NSEG; j++) {
      bool ge = (i >= kSegOffArr(j));
      s    = ge ? j : s;
      base = ge ? kSegOffArr(j) : base;
    }
    int off = i - base;
    const void* src = pk.p[3 + s];
    dst[i] = isf32 ? f2bf(((const float*)src)[off]) : ((const bf16*)src)[off];
  }
  // transposed copies: WT[k*N + n] = W[n*K + k]
  for (int j = gtid; j < TR_TOTAL; j += stride) {
    const void* src;
    int off;
    if (j < TR_WtcT)      { src = pk.p[17]; int jj = j;            off = (jj & 255) * 256 + (jj >> 8); }
    else if (j < TR_WltT) { src = pk.p[18]; int jj = j - TR_WtcT;  off = (jj & 255) * 256 + (jj >> 8); }
    else if (j < TR_WcvT) { src = pk.p[12]; int jj = j - TR_WltT;  off = (jj & 255) * 256 + (jj >> 8); }
    else                  { src = pk.p[14]; int jj = j - TR_WcvT;  off = (jj & 255) * 128 + (jj >> 8); }
    dst[TR_BASE + j] = isf32 ? f2bf(((const float*)src)[off]) : ((const bf16*)src)[off];
  }
  // hs poison: 0xFFFFFFFF (bf16 NaN pair) data-is-flag sentinel. 64MB.
  uint4 pv = make_uint4(0xFFFFFFFFu, 0xFFFFFFFFu, 0xFFFFFFFFu, 0xFFFFFFFFu);
  for (int i = gtid; i < (int)((size_t)T_SZ * B_SZ * H_SZ * 2 / 16); i += stride)
    hsp[i] = pv;
}

// ---------------------------------------------------------------------------
// inline x-frag gather helpers (round-10: idx software-pipelined).
// Thread (m, kt, qq) produces features [kt*32+qq*8, +8) of row (t, b).
// kt is wave-uniform (tid>>6) -> no divergence.
// ---------------------------------------------------------------------------
__device__ __forceinline__ short8 x_frag_cont(
    const void* __restrict__ cont_raw, bool isf32, int b, int t, int f) {
  long base = ((long)b * T_SZ + t) * 64 + (f - 64);
  if (isf32) {
    const float4* sp =
        reinterpret_cast<const float4*>((const float*)cont_raw + base);
    float4 x0 = sp[0], x1 = sp[1];
    union { short8 v; bf16 h[8]; } u;
    u.h[0] = f2bf(x0.x); u.h[1] = f2bf(x0.y); u.h[2] = f2bf(x0.z); u.h[3] = f2bf(x0.w);
    u.h[4] = f2bf(x1.x); u.h[5] = f2bf(x1.y); u.h[6] = f2bf(x1.z); u.h[7] = f2bf(x1.w);
    return u.v;
  } else {
    return *reinterpret_cast<const short8*>((const bf16*)cont_raw + base);
  }
}
// emb path with PRE-LOADED idx (no dependent chain inside the step)
__device__ __forceinline__ short8 x_frag_idx(
    const void* __restrict__ cont_raw, bool isf32, int idx,
    const bf16* __restrict__ e0, const bf16* __restrict__ e1,
    int b, int t, int kt, int qq) {
  int f = kt * 32 + qq * 8;
  if (kt == 0)      return *reinterpret_cast<const short8*>(e0 + idx * 32 + f);
  else if (kt == 1) return *reinterpret_cast<const short8*>(e1 + idx * 32 + (f - 32));
  else              return x_frag_cont(cont_raw, isf32, b, t, f);
}

// ---------------------------------------------------------------------------
// 2) LSTM — round-3 sync structure (frozen) + inline gather with the cat-
//    index SOFTWARE-PIPELINED (round-10). Round-9 evidence: the in-step
//    dependent chain (seq_cat load -> wait -> emb load) cost +66us
//    (0.5us/step exposed latency). Now idx(t+1) is loaded at step t-1 into
//    a register, so at step t BOTH prefetch loads (emb frag via resident
//    idx; idx(t+2)) are independent and issue back-to-back at step start —
//    round-8's issue shape, with k_gather + 32MB seqd still eliminated.
// ---------------------------------------------------------------------------
#define HPOISON 0xFFFFFFFFu
__global__ __launch_bounds__(512, 2) void k_lstm(
    const void* __restrict__ cont_raw, const int* __restrict__ seq_cat,
    const bf16* __restrict__ emb_s0, const bf16* __restrict__ emb_s1,
    const bf16* __restrict__ Wih, const bf16* __restrict__ Whh,
    const bf16* __restrict__ bih, const bf16* __restrict__ bhh,
    bf16* __restrict__ hs, const unsigned* __restrict__ probe) {
  __shared__ short8 hsh[2][8 * 64];   // 16KB: h_{t-1} A-frags, double-buffered
  __shared__ short8 xsh[2][4 * 64];   // 8KB:  x_t A-frags, double-buffered
  bool isf32 = ((probe[0] & 0xFFFFu) == 0u);
  int tid  = threadIdx.x;
  int w    = tid >> 6, lane = tid & 63;
  int quad = lane >> 4, l15 = lane & 15;
  int bid  = blockIdx.x;
  int gid  = bid & 63;   // group (16 batch rows)
  int rank = bid >> 6;   // 0..1 (owns h-units [rank*128, +128))
  int peer = 1 - rank;
  long b0  = (long)gid * 16;
  int hup = w * 16 + l15;        // rank-local h-unit this lane owns (0..127)
  int hu  = rank * 128 + hup;    // global h-unit (0..255)
  // prefetch-thread coords (tid<256): m=tid&15, kt=tid>>6 (wave-uniform)
  int pm = tid & 15, pkt = tid >> 6, pqq = (tid >> 4) & 3;
  int pb = (int)(b0 + pm);
  bool isemb = (tid < 256) && (pkt < 2);

  { short8 z = {0,0,0,0,0,0,0,0}; hsh[0][tid] = z; }  // h_{-1} = 0 (both halves)

  // per-lane bias for this lane's 4 gates of h-unit hu
  float bia[4];
#pragma unroll
  for (int i = 0; i < 4; ++i) {
    int grow = i * H_SZ + hu;
    bia[i] = bf2f(bih[grow]) + bf2f(bhh[grow]);
  }

  // resident weights: gate i rows i*H + rank*128 + hup. All indices
  // compile-time (full unroll) -> registers/AGPRs (r8 verified).
  short8 wif[4][4];    // Wih  frags
  short8 whfS[4][4];   // Whh, self-half kts
  short8 whfP[4][4];   // Whh, peer-half kts
#pragma unroll
  for (int i = 0; i < 4; ++i) {
    long grow = (long)(i * H_SZ + rank * 128 + hup);
#pragma unroll
    for (int kt = 0; kt < 4; ++kt) {
      wif[i][kt] = *reinterpret_cast<const short8*>(
          Wih + grow * DIN + kt * 32 + quad * 8);
      whfS[i][kt] = *reinterpret_cast<const short8*>(
          Whh + grow * H_SZ + (rank * 4 + kt) * 32 + quad * 8);
      whfP[i][kt] = *reinterpret_cast<const short8*>(
          Whh + grow * H_SZ + (peer * 4 + kt) * 32 + quad * 8);
    }
  }
  // prologue: stage x_0 (idx(0) loaded here, off the critical path) and
  // seed idxn = idx(1) for the first loop iteration's prefetch.
  int idxn = 0;
  if (tid < 256) {
    int idx0 = isemb ? seq_cat[(pb * T_SZ + 0) * 2 + pkt] : 0;
    xsh[0][tid] = x_frag_idx(cont_raw, isf32, idx0, emb_s0, emb_s1,
                             pb, 0, pkt, pqq);
    if (isemb) idxn = seq_cat[(pb * T_SZ + 1) * 2 + pkt];
  }
  float c[4] = {0.f, 0.f, 0.f, 0.f};
  __syncthreads();

  for (int t = 0; t < T_SZ; ++t) {
    int cur = t & 1, nxt = cur ^ 1;
    // prefetch x_{t+1} using register-resident idxn (independent load) and
    // load idx(t+2) into idxn2 (independent load) — no in-step dependency.
    short8 xpre;
    int idxn2 = idxn;
    bool dopre = (t + 1 < T_SZ) & (tid < 256);
    if (dopre) {
      xpre = x_frag_idx(cont_raw, isf32, idxn, emb_s0, emb_s1,
                        pb, t + 1, pkt, pqq);
      if (isemb) {
        int t2 = (t + 2 < T_SZ) ? t + 2 : t + 1;  // clamped dead load at tail
        idxn2 = seq_cat[(pb * T_SZ + t2) * 2 + pkt];
      }
    }

    f32x4 acc[4];
#pragma unroll
    for (int i = 0; i < 4; ++i) acc[i] = {0.f, 0.f, 0.f, 0.f};

    // x-projection (resident wif)
#pragma unroll
    for (int kt = 0; kt < 4; ++kt) {
      short8 ax = xsh[cur][kt * 64 + lane];
#pragma unroll
      for (int i = 0; i < 4; ++i)
        acc[i] = __builtin_amdgcn_mfma_f32_16x16x32_bf16(ax, wif[i][kt], acc[i], 0, 0, 0);
    }
    // self-half h recurrence (scattered locally last step via LDS)
#pragma unroll
    for (int kt = 0; kt < 4; ++kt) {
      short8 ah = hsh[cur][(rank * 4 + kt) * 64 + lane];
#pragma unroll
      for (int i = 0; i < 4; ++i)
        acc[i] = __builtin_amdgcn_mfma_f32_16x16x32_bf16(ah, whfS[i][kt], acc[i], 0, 0, 0);
    }

    if (t > 0) {
      // staging waves: poll peer's h_{t-1} half DIRECTLY on the data
      // (poison 0xFFFFFFFF = bf16 NaN pair, unreachable for sigm*tanh).
      if (tid < 256) {
        int m = tid >> 4, seg = tid & 15;
        const unsigned* src = reinterpret_cast<const unsigned*>(
            hs + ((long)(t - 1) * B_SZ + b0 + m) * H_SZ + peer * 128 + seg * 8);
        unsigned d0, d1, d2, d3;
        do {
          d0 = __hip_atomic_load(src + 0, __ATOMIC_RELAXED, __HIP_MEMORY_SCOPE_AGENT);
          d1 = __hip_atomic_load(src + 1, __ATOMIC_RELAXED, __HIP_MEMORY_SCOPE_AGENT);
          d2 = __hip_atomic_load(src + 2, __ATOMIC_RELAXED, __HIP_MEMORY_SCOPE_AGENT);
          d3 = __hip_atomic_load(src + 3, __ATOMIC_RELAXED, __HIP_MEMORY_SCOPE_AGENT);
        } while (d0 == HPOISON || d1 == HPOISON || d2 == HPOISON || d3 == HPOISON);
        union { unsigned u[4]; short8 s; } cv;
        cv.u[0] = d0; cv.u[1] = d1; cv.u[2] = d2; cv.u[3] = d3;
        // 16B read lands exactly on one A-frag: kt = peer*4 + (seg>>2),
        // lane = (seg&3)*16 + m
        hsh[cur][(peer * 4 + (seg >> 2)) * 64 + (seg & 3) * 16 + m] = cv.s;
      }
      __syncthreads();  // syncB
    }
    // peer-half h recurrence
#pragma unroll
    for (int kt = 0; kt < 4; ++kt) {
      short8 ah = hsh[cur][(peer * 4 + kt) * 64 + lane];
#pragma unroll
      for (int i = 0; i < 4; ++i)
        acc[i] = __builtin_amdgcn_mfma_f32_16x16x32_bf16(ah, whfP[i][kt], acc[i], 0, 0, 0);
    }

    // elementwise, fully in-register: lane owns (m = quad*4+r, hu) for r=0..3
    bf16* hbn = reinterpret_cast<bf16*>(&hsh[nxt][0]);
    unsigned hpk[4];
#pragma unroll
    for (int r = 0; r < 4; ++r) {
      float iv = sigm(acc[0][r] + bia[0]);
      float fv = sigm(acc[1][r] + bia[1]);
      float gv = ftanh(acc[2][r] + bia[2]);
      float ov = sigm(acc[3][r] + bia[3]);
      c[r] = fv * c[r] + iv * gv;
      bf16 hv = f2bf(ov * ftanh(c[r]));
      int m = quad * 4 + r;
      // local scatter into next step's A-frag buffer (LDS)
      hbn[(((hu >> 5) * 64) + ((hu >> 3) & 3) * 16 + m) * 8 + (hu & 7)] = hv;
      // pack (hu, hu+1) into a dword for the MALL publish (even l15 lanes)
      unsigned hraw = (unsigned)*reinterpret_cast<unsigned short*>(&hv);
      unsigned nb = (unsigned)__shfl_down((int)hraw, 1, 64);
      hpk[r] = hraw | (nb << 16);
    }
    if (dopre) { xsh[nxt][tid] = xpre; idxn = idxn2; }  // land prefetch + idx
    __syncthreads();  // syncD (fences LDS for next step; drains prior VMEM)
    // publish h_t AFTER the barrier: off the critical path, retires under
    // next step's compute. Peer polls the data itself.
    if ((l15 & 1) == 0) {
#pragma unroll
      for (int r = 0; r < 4; ++r) {
        int m = quad * 4 + r;
        unsigned* dst = reinterpret_cast<unsigned*>(
            hs + ((long)t * B_SZ + b0 + m) * H_SZ + hu);
        __hip_atomic_store(dst, hpk[r], __ATOMIC_RELAXED,
                           __HIP_MEMORY_SCOPE_AGENT);
      }
    }
  }
}

// ---------------------------------------------------------------------------
// 3) TPA stage A (r8-tuned, kept): u = hn @ W_tpa; w2 = W_conv^T u; c0.
// ---------------------------------------------------------------------------
__global__ __launch_bounds__(256) void k_u(
    const bf16* __restrict__ hs, const bf16* __restrict__ W_tpa,
    const bf16* __restrict__ W_conv, const bf16* __restrict__ b_conv,
    float* __restrict__ w2, float* __restrict__ c0) {
  __shared__ float hn_sh[8][256];
  __shared__ float u_sh[8][256];
  __shared__ float wred[4][8];
  int tid = threadIdx.x;
  long b0 = (long)blockIdx.x * 8;
#pragma unroll
  for (int r = 0; r < 8; r++)
    hn_sh[r][tid] = bf2f(hs[((long)(T_SZ - 1) * B_SZ + b0 + r) * H_SZ + tid]);
  __syncthreads();
  float u[8] = {0,0,0,0,0,0,0,0};
  for (int kk = 0; kk < 32; kk++) {
    float wv[8];
#pragma unroll
    for (int q = 0; q < 8; q++)
      wv[q] = bf2f(W_tpa[(kk * 8 + q) * H_SZ + tid]);
#pragma unroll
    for (int r = 0; r < 8; r++) {
      const float4* hp = reinterpret_cast<const float4*>(&hn_sh[r][kk * 8]);
      float4 h0 = hp[0], h1 = hp[1];
      u[r] += h0.x * wv[0]; u[r] += h0.y * wv[1];
      u[r] += h0.z * wv[2]; u[r] += h0.w * wv[3];
      u[r] += h1.x * wv[4]; u[r] += h1.y * wv[5];
      u[r] += h1.z * wv[6]; u[r] += h1.w * wv[7];
    }
  }
  float bc = bf2f(b_conv[tid]);
  float p[8];
#pragma unroll
  for (int r = 0; r < 8; r++) { u_sh[r][tid] = u[r]; p[r] = u[r] * bc; }
#pragma unroll
  for (int d = 32; d > 0; d >>= 1)
#pragma unroll
    for (int r = 0; r < 8; r++) p[r] += __shfl_down(p[r], d, 64);
  if ((tid & 63) == 0)
#pragma unroll
    for (int r = 0; r < 8; r++) wred[tid >> 6][r] = p[r];
  __syncthreads();
  if (tid < 8)
    c0[b0 + tid] = wred[0][tid] + wred[1][tid] + wred[2][tid] + wred[3][tid];
  if (tid < T_SZ) {
    float a[8] = {0,0,0,0,0,0,0,0};
    for (int jj = 0; jj < 32; jj++) {
      float wv[8];
#pragma unroll
      for (int q = 0; q < 8; q++)
        wv[q] = bf2f(W_conv[(jj * 8 + q) * T_SZ + tid]);
#pragma unroll
      for (int r = 0; r < 8; r++) {
        const float4* up = reinterpret_cast<const float4*>(&u_sh[r][jj * 8]);
        float4 u0 = up[0], u1 = up[1];
        a[r] += u0.x * wv[0]; a[r] += u0.y * wv[1];
        a[r] += u0.z * wv[2]; a[r] += u0.w * wv[3];
        a[r] += u1.x * wv[4]; a[r] += u1.y * wv[5];
        a[r] += u1.z * wv[6]; a[r] += u1.w * wv[7];
      }
    }
#pragma unroll
    for (int r = 0; r < 8; r++) w2[(b0 + r) * T_SZ + tid] = a[r];
  }
}

// ---------------------------------------------------------------------------
// 4) Fused alpha+s (r8-measured, kept): one block per b; hs slice in LDS.
// ---------------------------------------------------------------------------
__global__ __launch_bounds__(256) void k_alphas(
    const bf16* __restrict__ hs, const float* __restrict__ w2,
    const float* __restrict__ c0, float* __restrict__ asum,
    float* __restrict__ sbuf) {
  __shared__ unsigned hc[128 * 129];  // 66KB; row t at hc[t*129], 128 words
  __shared__ float w2s[T_SZ];
  __shared__ float ash[H_SZ];
  __shared__ float red[256];
  int b = blockIdx.x, tid = threadIdx.x;
#pragma unroll
  for (int p = 0; p < 16; p++) {
    int task = p * 256 + tid;
    int row = task >> 5, seg = task & 31;
    short8 v = *reinterpret_cast<const short8*>(
        hs + ((long)row * B_SZ + b) * H_SZ + seg * 8);
    union { short8 s; unsigned u[4]; } cv; cv.s = v;
#pragma unroll
    for (int k = 0; k < 4; k++) hc[row * 129 + seg * 4 + k] = cv.u[k];
  }
  if (tid < T_SZ) w2s[tid] = w2[b * T_SZ + tid];
  __syncthreads();
  {
    float ap = c0[b];
    int wi = tid >> 1, hi = tid & 1;
    for (int t = 0; t < T_SZ; t++) {
      unsigned uv = hc[t * 129 + wi];
      unsigned short h16 = hi ? (unsigned short)(uv >> 16) : (unsigned short)(uv & 0xFFFF);
      float hvf = __bfloat162float(*reinterpret_cast<bf16*>(&h16));
      ap += hvf * w2s[t];
    }
    float a = sigm(ap);
    ash[tid] = a;
    red[tid] = a;
  }
  __syncthreads();
  for (int s = 128; s > 0; s >>= 1) {
    if (tid < s) red[tid] += red[tid + s];
    __syncthreads();
  }
  if (tid == 0) asum[b] = red[0];
  if (tid < T_SZ) {
    float acc = 0.f;
    for (int k = 0; k < 128; k++) {
      int wi = (k + tid) & 127;
      unsigned uv = hc[tid * 129 + wi];
      unsigned short lo16 = (unsigned short)(uv & 0xFFFF);
      unsigned short hi16 = (unsigned short)(uv >> 16);
      float lo = __bfloat162float(*reinterpret_cast<bf16*>(&lo16));
      float hi = __bfloat162float(*reinterpret_cast<bf16*>(&hi16));
      acc += ash[2 * wi] * lo + ash[2 * wi + 1] * hi;
    }
    sbuf[b * T_SZ + tid] = acc;
  }
}

// ---------------------------------------------------------------------------
// 5) k_finmlp — round-9 fusion (kept verbatim): k_fin + k_mlp in one kernel;
//    fin lives in LDS a_sh[pos*8+r]; fin round-trip + a launch eliminated.
// ---------------------------------------------------------------------------
__global__ __launch_bounds__(512) void k_finmlp(
    const bf16* __restrict__ hs, const float* __restrict__ sbuf,
    const float* __restrict__ asum, const bf16* __restrict__ WcvT,
    const bf16* __restrict__ b_conv, const bf16* __restrict__ WthT,
    const bf16* __restrict__ WtcT, const bf16* __restrict__ WltT,
    const bf16* __restrict__ b_ltd, const int* __restrict__ ns_cat,
    const bf16* __restrict__ emb_ns0, const bf16* __restrict__ emb_ns1,
    const bf16* __restrict__ ns_cont, const bf16* __restrict__ W_f1,
    const bf16* __restrict__ b_f1, const bf16* __restrict__ g1,
    const bf16* __restrict__ be1, const bf16* __restrict__ m1,
    const bf16* __restrict__ v1, const bf16* __restrict__ W_f2,
    const bf16* __restrict__ b_f2, const bf16* __restrict__ g2,
    const bf16* __restrict__ be2, const bf16* __restrict__ m2,
    const bf16* __restrict__ v2, const bf16* __restrict__ W_out,
    const bf16* __restrict__ b_out, void* __restrict__ d_out_raw,
    const unsigned* __restrict__ probe) {
  bool isf32 = ((probe[0] & 0xFFFFu) == 0u);
  __shared__ float s_sh[8][128];      // 4KB
  __shared__ float hn_sh[8][256];     // 8KB
  __shared__ float vt_sh[8][256];     // 8KB
  __shared__ float a_sh[FINW * 8];    // 21.5KB: fin, transposed a_sh[pos*8+r]
  __shared__ float x1t[512 * 8];      // 16KB
  __shared__ float x2t[256 * 8];      // 8KB   -> total ~65.5KB
  int tid = threadIdx.x;
  int h = tid & 255, rh = tid >> 8;   // this thread owns rows r = rh*4..rh*4+3
  long b0 = (long)blockIdx.x * 8;
  auto store2 = [&](int r, int pos, float v) {
    a_sh[pos * 8 + r] = v;
    if (isf32)
      ((float*)d_out_raw + 65536)[(b0 + r) * FINW + pos] = v;
    else
      ((bf16*)d_out_raw + 65536)[(b0 + r) * FINW + pos] = f2bf(v);
  };
  if (tid < 128)
#pragma unroll
    for (int r = 0; r < 8; r++) s_sh[r][tid] = sbuf[(b0 + r) * T_SZ + tid];
#pragma unroll
  for (int rr = 0; rr < 4; rr++) {
    int r = rh * 4 + rr;
    hn_sh[r][h] = bf2f(hs[((long)(T_SZ - 1) * B_SZ + b0 + r) * H_SZ + h]);
  }
  __syncthreads();
  float vt[4] = {0, 0, 0, 0};
  for (int tt = 0; tt < 16; tt++) {
    float wv[8];
#pragma unroll
    for (int q = 0; q < 8; q++)
      wv[q] = bf2f(WcvT[(tt * 8 + q) * H_SZ + h]);
#pragma unroll
    for (int rr = 0; rr < 4; rr++) {
      int r = rh * 4 + rr;
      const float4* sp = reinterpret_cast<const float4*>(&s_sh[r][tt * 8]);
      float4 s0 = sp[0], s1 = sp[1];
      vt[rr] += wv[0] * s0.x; vt[rr] += wv[1] * s0.y;
      vt[rr] += wv[2] * s0.z; vt[rr] += wv[3] * s0.w;
      vt[rr] += wv[4] * s1.x; vt[rr] += wv[5] * s1.y;
      vt[rr] += wv[6] * s1.z; vt[rr] += wv[7] * s1.w;
    }
  }
  float bc = bf2f(b_conv[h]);
#pragma unroll
  for (int rr = 0; rr < 4; rr++) {
    int r = rh * 4 + rr;
    vt[rr] += bc * asum[b0 + r];
    vt_sh[r][h] = vt[rr];
  }
  __syncthreads();
  float htp[4] = {0, 0, 0, 0}, sq[4] = {0, 0, 0, 0};
  for (int kk = 0; kk < 32; kk++) {
    float wh[8], wc[8], wl[8];
#pragma unroll
    for (int q = 0; q < 8; q++) {
      int k = kk * 8 + q;
      wh[q] = bf2f(WthT[k * H_SZ + h]);
      wc[q] = bf2f(WtcT[k * H_SZ + h]);
      wl[q] = bf2f(WltT[k * H_SZ + h]);
    }
#pragma unroll
    for (int rr = 0; rr < 4; rr++) {
      int r = rh * 4 + rr;
      const float4* hp = reinterpret_cast<const float4*>(&hn_sh[r][kk * 8]);
      const float4* vp = reinterpret_cast<const float4*>(&vt_sh[r][kk * 8]);
      float4 h0 = hp[0], h1 = hp[1], v0 = vp[0], v1 = vp[1];
      htp[rr] += h0.x * wh[0] + v0.x * wc[0]; sq[rr] += h0.x * wl[0];
      htp[rr] += h0.y * wh[1] + v0.y * wc[1]; sq[rr] += h0.y * wl[1];
      htp[rr] += h0.z * wh[2] + v0.z * wc[2]; sq[rr] += h0.z * wl[2];
      htp[rr] += h0.w * wh[3] + v0.w * wc[3]; sq[rr] += h0.w * wl[3];
      htp[rr] += h1.x * wh[4] + v1.x * wc[4]; sq[rr] += h1.x * wl[4];
      htp[rr] += h1.y * wh[5] + v1.y * wc[5]; sq[rr] += h1.y * wl[5];
      htp[rr] += h1.z * wh[6] + v1.z * wc[6]; sq[rr] += h1.z * wl[6];
      htp[rr] += h1.w * wh[7] + v1.w * wc[7]; sq[rr] += h1.w * wl[7];
    }
  }
  float bl = bf2f(b_ltd[h]);
#pragma unroll
  for (int rr = 0; rr < 4; rr++) {
    int r = rh * 4 + rr;
    store2(r, 160 + h, sq[rr] + bl);
    store2(r, 416 + h, htp[rr]);
  }
  if (tid < 160) {
#pragma unroll
    for (int r = 0; r < 8; r++) {
      long b = b0 + r;
      float v;
      if (tid < 64)       v = bf2f(emb_ns0[(long)ns_cat[b * 2 + 0] * 64 + tid]);
      else if (tid < 128) v = bf2f(emb_ns1[(long)ns_cat[b * 2 + 1] * 64 + tid - 64]);
      else                v = bf2f(ns_cont[b * 32 + tid - 128]);
      store2(r, tid, v);
    }
  }
  __syncthreads();
  // ================= MLP phase (identical to round-8 k_mlp) =================
  {  // layer 1: n = tid (512 outputs), k = 672 = 168*4
    int n = tid;
    float acc[8] = {0, 0, 0, 0, 0, 0, 0, 0};
    const short4v* wr4 = reinterpret_cast<const short4v*>(W_f1 + (long)n * FINW);
    for (int kk = 0; kk < FINW / 4; kk++) {
      short4v w4 = wr4[kk];
#pragma unroll
      for (int j = 0; j < 4; j++) {
        float wv = bfraw2f((unsigned short)w4[j]);
        const float4* ap = reinterpret_cast<const float4*>(&a_sh[(kk * 4 + j) * 8]);
        float4 a0 = ap[0], a1 = ap[1];
        acc[0] += wv * a0.x; acc[1] += wv * a0.y;
        acc[2] += wv * a0.z; acc[3] += wv * a0.w;
        acc[4] += wv * a1.x; acc[5] += wv * a1.y;
        acc[6] += wv * a1.z; acc[7] += wv * a1.w;
      }
    }
    float bb = bf2f(b_f1[n]);
    float scale = bf2f(g1[n]) * rsqrtf(bf2f(v1[n]) + 1e-5f);
    float mm = bf2f(m1[n]), bee = bf2f(be1[n]);
#pragma unroll
    for (int r = 0; r < 8; r++) {
      float x = acc[r] + bb;
      x = x > 0.f ? x : 0.f;
      x1t[n * 8 + r] = (x - mm) * scale + bee;
    }
  }
  __syncthreads();
  if (tid < 256) {  // layer 2: n = tid (256 outputs), k = 512 = 64*8
    int n = tid;
    float acc[8] = {0, 0, 0, 0, 0, 0, 0, 0};
    const short8* wr8 = reinterpret_cast<const short8*>(W_f2 + (long)n * 512);
    for (int kk = 0; kk < 64; kk++) {
      short8 w8 = wr8[kk];
#pragma unroll
      for (int j = 0; j < 8; j++) {
        float wv = bfraw2f((unsigned short)w8[j]);
        const float4* ap = reinterpret_cast<const float4*>(&x1t[(kk * 8 + j) * 8]);
        float4 a0 = ap[0], a1 = ap[1];
        acc[0] += wv * a0.x; acc[1] += wv * a0.y;
        acc[2] += wv * a0.z; acc[3] += wv * a0.w;
        acc[4] += wv * a1.x; acc[5] += wv * a1.y;
        acc[6] += wv * a1.z; acc[7] += wv * a1.w;
      }
    }
    float bb = bf2f(b_f2[n]);
    float scale = bf2f(g2[n]) * rsqrtf(bf2f(v2[n]) + 1e-5f);
    float mm = bf2f(m2[n]), bee = bf2f(be2[n]);
#pragma unroll
    for (int r = 0; r < 8; r++) {
      float x = acc[r] + bb;
      x = x > 0.f ? x : 0.f;
      x2t[n * 8 + r] = (x - mm) * scale + bee;
    }
  }
  __syncthreads();
  if (tid < 64) {  // layer 3: n = tid (64 outputs), k = 256 = 32*8
    int n = tid;
    float acc[8] = {0, 0, 0, 0, 0, 0, 0, 0};
    const short8* wr8 = reinterpret_cast<const short8*>(W_out + (long)n * H_SZ);
    for (int kk = 0; kk < 32; kk++) {
      short8 w8 = wr8[kk];
#pragma unroll
      for (int j = 0; j < 8; j++) {
        float wv = bfraw2f((unsigned short)w8[j]);
        const float4* ap = reinterpret_cast<const float4*>(&x2t[(kk * 8 + j) * 8]);
        float4 a0 = ap[0], a1 = ap[1];
        acc[0] += wv * a0.x; acc[1] += wv * a0.y;
        acc[2] += wv * a0.z; acc[3] += wv * a0.w;
        acc[4] += wv * a1.x; acc[5] += wv * a1.y;
        acc[6] += wv * a1.z; acc[7] += wv * a1.w;
      }
    }
    float bb = bf2f(b_out[n]);
#pragma unroll
    for (int r = 0; r < 8; r++) {
      float x = acc[r] + bb;
      x = x > 0.f ? x : 0.f;
      if (isf32)
        ((float*)d_out_raw)[(b0 + r) * 64 + n] = x;
      else
        ((bf16*)d_out_raw)[(b0 + r) * 64 + n] = f2bf(x);
    }
  }
}

// ---------------------------------------------------------------------------
extern "C" void kernel_launch(void* const* d_in, const int* in_sizes, int n_in,
                              void* d_out, int out_size, void* d_ws,
                              size_t ws_size, hipStream_t stream) {
  const int* seq_cat = (const int*)d_in[1];
  const int* ns_cat  = (const int*)d_in[2];
  const unsigned* probe = (const unsigned*)d_in[24];  // v1 = ones

  // workspace layout — total ~70MB (seqd + fin eliminated)
  char* ws = (char*)d_ws;
  bf16* hsb   = (bf16*)ws;  ws += (size_t)T_SZ * B_SZ * H_SZ * 2;  // 64MB
  bf16* arena = (bf16*)ws;  ws += (size_t)ARENA_TOTAL2 * 2;        // ~4.4MB
  float* w2   = (float*)ws; ws += (size_t)B_SZ * T_SZ * 4;
  float* c0   = (float*)ws; ws += (size_t)B_SZ * 4;
  float* asum = (float*)ws; ws += (size_t)B_SZ * 4;
  float* sbuf = (float*)ws; ws += (size_t)B_SZ * T_SZ * 4;

  const bf16* c_ns_cont = arena + 0;
  const bf16* c_emb_ns0 = arena + 32768;
  const bf16* c_emb_ns1 = arena + 672768;
  const bf16* c_emb_s0  = arena + 736768;
  const bf16* c_emb_s1  = arena + 768768;
  const bf16* c_W_ih    = arena + 784768;
  const bf16* c_W_hh    = arena + 915840;
  const bf16* c_b_ih    = arena + 1177984;
  const bf16* c_b_hh    = arena + 1179008;
  const bf16* c_b_ltd   = arena + 1245568;
  const bf16* c_W_conv  = arena + 1245824;
  const bf16* c_b_conv  = arena + 1278592;
  const bf16* c_W_tpa   = arena + 1278848;
  const bf16* c_W_f1    = arena + 1475456;
  const bf16* c_b_f1    = arena + 1819520;
  const bf16* c_g1      = arena + 1820032;
  const bf16* c_be1     = arena + 1820544;
  const bf16* c_m1      = arena + 1821056;
  const bf16* c_v1      = arena + 1821568;
  const bf16* c_W_f2    = arena + 1822080;
  const bf16* c_b_f2    = arena + 1953152;
  const bf16* c_g2      = arena + 1953408;
  const bf16* c_be2     = arena + 1953664;
  const bf16* c_m2      = arena + 1953920;
  const bf16* c_v2      = arena + 1954176;
  const bf16* c_W_out   = arena + 1954432;
  const bf16* c_b_out   = arena + 1970816;
  const bf16* c_WthT    = arena + TR_BASE + TR_WthT;
  const bf16* c_WtcT    = arena + TR_BASE + TR_WtcT;
  const bf16* c_WltT    = arena + TR_BASE + TR_WltT;
  const bf16* c_WcvT    = arena + TR_BASE + TR_WcvT;

  Ptrs pk;
  for (int i = 0; i < 33; i++) pk.p[i] = d_in[i];

  // k_convert also poisons hs (data-is-flag sentinel; hs write-once/cell)
  k_convert<<<dim3(512), 256, 0, stream>>>(pk, arena, (uint4*)hsb);
  k_lstm<<<dim3(128), 512, 0, stream>>>(d_in[0], seq_cat, c_emb_s0, c_emb_s1,
                                        c_W_ih, c_W_hh, c_b_ih, c_b_hh, hsb,
                                        probe);
  k_u<<<dim3(B_SZ / 8), 256, 0, stream>>>(hsb, c_W_tpa, c_W_conv, c_b_conv, w2, c0);
  k_alphas<<<dim3(B_SZ), 256, 0, stream>>>(hsb, w2, c0, asum, sbuf);
  k_finmlp<<<dim3(B_SZ / 8), 512, 0, stream>>>(
      hsb, sbuf, asum, c_WcvT, c_b_conv, c_WthT, c_WtcT, c_WltT, c_b_ltd,
      ns_cat, c_emb_ns0, c_emb_ns1, c_ns_cont, c_W_f1, c_b_f1, c_g1, c_be1,
      c_m1, c_v1, c_W_f2, c_b_f2, c_g2, c_be2, c_m2, c_v2, c_W_out, c_b_out,
      d_out, probe);
}

// Round 11
// 636.793 us; speedup vs baseline: 1.1122x; 1.1122x over previous
//
#include <hip/hip_runtime.h>
#include <hip/hip_bf16.h>
#include <math.h>

// Problem constants
#define B_SZ 1024
#define T_SZ 128
#define H_SZ 256
#define DIN  128
#define G4   1024   // 4*H
#define FINW 672

using bf16   = __hip_bfloat16;
using short8 = __attribute__((ext_vector_type(8))) short;  // 8 bf16 (4 VGPRs)
using short4v = __attribute__((ext_vector_type(4))) short;
using f32x4  = __attribute__((ext_vector_type(4))) float;

__device__ __forceinline__ float bf2f(bf16 x) { return __bfloat162float(x); }
__device__ __forceinline__ bf16  f2bf(float x) { return __float2bfloat16(x); }
__device__ __forceinline__ float sigm(float x) { return 1.0f / (1.0f + __expf(-x)); }
__device__ __forceinline__ float ftanh(float x) { return 2.0f / (1.0f + __expf(-2.0f * x)) - 1.0f; }
__device__ __forceinline__ float bfraw2f(unsigned short r) {
  unsigned u = ((unsigned)r) << 16;
  return *reinterpret_cast<float*>(&u);
}

struct Ptrs { const void* p[33]; };

#define NSEG 30
__device__ __host__ constexpr int kSegOffArr(int i) {
  constexpr int off[NSEG + 1] = {
      0,       32768,   672768,  736768,  768768,  784768,  915840,
      1177984, 1179008, 1180032, 1245568, 1245824, 1278592, 1278848,
      1344384, 1409920, 1475456, 1819520, 1820032, 1820544, 1821056,
      1821568, 1822080, 1953152, 1953408, 1953664, 1953920, 1954176,
      1954432, 1970816, 1970880};
  return off[i];
}
#define ARENA_TOTAL 1970880
// transposed-weight extension region: WT[k][n] layouts for k_finmlp
#define TR_BASE   1970880
#define TR_WthT   0        // 65536  (W_tpa_h^T, src p[17])
#define TR_WtcT   65536    // 65536  (W_tpa_c^T, src p[18])
#define TR_WltT   131072   // 65536  (W_ltd^T,   src p[12])
#define TR_WcvT   196608   // 32768  (W_conv^T,  src p[14])
#define TR_TOTAL  229376
#define ARENA_TOTAL2 (ARENA_TOTAL + TR_TOTAL)

// ---------------------------------------------------------------------------
// 0) Convert float inputs to bf16 arena + transposed weight copies + hs
//    poison (fused; no separate memset launch). Round-9 version, kept.
// ---------------------------------------------------------------------------
__global__ __launch_bounds__(256) void k_convert(Ptrs pk, bf16* __restrict__ dst,
                                                 uint4* __restrict__ hsp) {
  bool isf32 = ((((const unsigned*)pk.p[24])[0] & 0xFFFFu) == 0u);
  int stride = gridDim.x * blockDim.x;
  int gtid = blockIdx.x * blockDim.x + threadIdx.x;
  for (int i = gtid; i < ARENA_TOTAL; i += stride) {
    int s = 0, base = 0;
#pragma unroll
    for (int j = 1; j < NSEG; j++) {
      bool ge = (i >= kSegOffArr(j));
      s    = ge ? j : s;
      base = ge ? kSegOffArr(j) : base;
    }
    int off = i - base;
    const void* src = pk.p[3 + s];
    dst[i] = isf32 ? f2bf(((const float*)src)[off]) : ((const bf16*)src)[off];
  }
  // transposed copies: WT[k*N + n] = W[n*K + k]
  for (int j = gtid; j < TR_TOTAL; j += stride) {
    const void* src;
    int off;
    if (j < TR_WtcT)      { src = pk.p[17]; int jj = j;            off = (jj & 255) * 256 + (jj >> 8); }
    else if (j < TR_WltT) { src = pk.p[18]; int jj = j - TR_WtcT;  off = (jj & 255) * 256 + (jj >> 8); }
    else if (j < TR_WcvT) { src = pk.p[12]; int jj = j - TR_WltT;  off = (jj & 255) * 256 + (jj >> 8); }
    else                  { src = pk.p[14]; int jj = j - TR_WcvT;  off = (jj & 255) * 128 + (jj >> 8); }
    dst[TR_BASE + j] = isf32 ? f2bf(((const float*)src)[off]) : ((const bf16*)src)[off];
  }
  // hs poison: 0xFFFFFFFF (bf16 NaN pair) data-is-flag sentinel. 64MB.
  uint4 pv = make_uint4(0xFFFFFFFFu, 0xFFFFFFFFu, 0xFFFFFFFFu, 0xFFFFFFFFu);
  for (int i = gtid; i < (int)((size_t)T_SZ * B_SZ * H_SZ * 2 / 16); i += stride)
    hsp[i] = pv;
}

// ---------------------------------------------------------------------------
// 1) Gather: seq_data[t*B + b][0:128] = [emb_s0(32) | emb_s1(32) | cont(64)]
//    REINSTATED (round-11). Rounds 9/10 evidence: both inline-gather variants
//    (dependent chain AND idx-pipelined) cost k_lstm +70..95us vs the staged
//    seqd path — the scattered emb reads/extra state perturb the 2-wave/SIMD
//    poll/barrier schedule regardless of dependency shape. k_lstm wants a
//    uniform single-load prefetch; stage seqd separately.
// ---------------------------------------------------------------------------
__global__ __launch_bounds__(256) void k_gather(
    const void* __restrict__ seq_cont_raw, const int* __restrict__ seq_cat,
    const bf16* __restrict__ emb_s0, const bf16* __restrict__ emb_s1,
    bf16* __restrict__ seq_out, const unsigned* __restrict__ probe) {
  bool isf32 = ((probe[0] & 0xFFFFu) == 0u);
  int gid = blockIdx.x * blockDim.x + threadIdx.x;
  int seg = gid & 15;
  int m   = gid >> 4;        // m = t*B + b
  int t   = m >> 10;
  int b   = m & 1023;
  bf16* dst = seq_out + (long)m * DIN + seg * 8;
  if (seg < 8) {
    const bf16* src;
    if (seg < 4) {
      int idx = seq_cat[(b * T_SZ + t) * 2 + 0];
      src = emb_s0 + idx * 32 + seg * 8;
    } else {
      int idx = seq_cat[(b * T_SZ + t) * 2 + 1];
      src = emb_s1 + idx * 32 + (seg - 4) * 8;
    }
    *reinterpret_cast<short8*>(dst) = *reinterpret_cast<const short8*>(src);
  } else {
    long base = ((long)b * T_SZ + t) * 64 + (seg - 8) * 8;
    if (isf32) {
      const float4* sp =
          reinterpret_cast<const float4*>((const float*)seq_cont_raw + base);
      float4 x0 = sp[0], x1 = sp[1];
      union { short8 v; bf16 h[8]; } u;
      u.h[0] = f2bf(x0.x); u.h[1] = f2bf(x0.y); u.h[2] = f2bf(x0.z); u.h[3] = f2bf(x0.w);
      u.h[4] = f2bf(x1.x); u.h[5] = f2bf(x1.y); u.h[6] = f2bf(x1.z); u.h[7] = f2bf(x1.w);
      *reinterpret_cast<short8*>(dst) = u.v;
    } else {
      *reinterpret_cast<short8*>(dst) =
          *reinterpret_cast<const short8*>((const bf16*)seq_cont_raw + base);
    }
  }
}

// ---------------------------------------------------------------------------
// 2) LSTM — EXACT round-3/round-8 kernel (best measured: 353-356us).
//    Frozen: lgkm-only barriers regressed (r7), L2 exchange refuted (r5/r6),
//    inline gather regressed (r9/r10). At the T*lambda MALL-exchange floor.
// ---------------------------------------------------------------------------
#define HPOISON 0xFFFFFFFFu
__global__ __launch_bounds__(512, 2) void k_lstm(
    const bf16* __restrict__ seq, const bf16* __restrict__ Wih,
    const bf16* __restrict__ Whh, const bf16* __restrict__ bih,
    const bf16* __restrict__ bhh, bf16* __restrict__ hs) {
  __shared__ short8 hsh[2][8 * 64];   // 16KB: h_{t-1} A-frags, double-buffered
  __shared__ short8 xsh[2][4 * 64];   // 8KB:  x_t A-frags, double-buffered
  int tid  = threadIdx.x;
  int w    = tid >> 6, lane = tid & 63;
  int quad = lane >> 4, l15 = lane & 15;
  int bid  = blockIdx.x;
  int gid  = bid & 63;   // group (16 batch rows)
  int rank = bid >> 6;   // 0..1 (owns h-units [rank*128, +128))
  int peer = 1 - rank;
  long b0  = (long)gid * 16;
  int hup = w * 16 + l15;        // rank-local h-unit this lane owns (0..127)
  int hu  = rank * 128 + hup;    // global h-unit (0..255)

  { short8 z = {0,0,0,0,0,0,0,0}; hsh[0][tid] = z; }  // h_{-1} = 0 (both halves)

  // per-lane bias for this lane's 4 gates of h-unit hu
  float bia[4];
#pragma unroll
  for (int i = 0; i < 4; ++i) {
    int grow = i * H_SZ + hu;
    bia[i] = bf2f(bih[grow]) + bf2f(bhh[grow]);
  }

  // resident weights: gate i rows i*H + rank*128 + hup. All indices
  // compile-time (full unroll) -> registers/AGPRs (r8 verified).
  short8 wif[4][4];    // Wih  frags
  short8 whfS[4][4];   // Whh, self-half kts
  short8 whfP[4][4];   // Whh, peer-half kts
#pragma unroll
  for (int i = 0; i < 4; ++i) {
    long grow = (long)(i * H_SZ + rank * 128 + hup);
#pragma unroll
    for (int kt = 0; kt < 4; ++kt) {
      wif[i][kt] = *reinterpret_cast<const short8*>(
          Wih + grow * DIN + kt * 32 + quad * 8);
      whfS[i][kt] = *reinterpret_cast<const short8*>(
          Whh + grow * H_SZ + (rank * 4 + kt) * 32 + quad * 8);
      whfP[i][kt] = *reinterpret_cast<const short8*>(
          Whh + grow * H_SZ + (peer * 4 + kt) * 32 + quad * 8);
    }
  }
  // prologue: stage x_0
  if (tid < 256)
    xsh[0][tid] = *reinterpret_cast<const short8*>(
        seq + (b0 + (tid & 15)) * DIN + (tid >> 6) * 32 +
        ((tid >> 4) & 3) * 8);
  float c[4] = {0.f, 0.f, 0.f, 0.f};
  __syncthreads();

  for (int t = 0; t < T_SZ; ++t) {
    int cur = t & 1, nxt = cur ^ 1;
    // issue x_{t+1} prefetch into regs (ds_write'd at end of step)
    short8 xpre;
    bool dopre = (t + 1 < T_SZ) & (tid < 256);
    if (dopre)
      xpre = *reinterpret_cast<const short8*>(
          seq + ((long)(t + 1) * B_SZ + b0 + (tid & 15)) * DIN +
          (tid >> 6) * 32 + ((tid >> 4) & 3) * 8);

    f32x4 acc[4];
#pragma unroll
    for (int i = 0; i < 4; ++i) acc[i] = {0.f, 0.f, 0.f, 0.f};

    // x-projection (resident wif)
#pragma unroll
    for (int kt = 0; kt < 4; ++kt) {
      short8 ax = xsh[cur][kt * 64 + lane];
#pragma unroll
      for (int i = 0; i < 4; ++i)
        acc[i] = __builtin_amdgcn_mfma_f32_16x16x32_bf16(ax, wif[i][kt], acc[i], 0, 0, 0);
    }
    // self-half h recurrence (scattered locally last step via LDS)
#pragma unroll
    for (int kt = 0; kt < 4; ++kt) {
      short8 ah = hsh[cur][(rank * 4 + kt) * 64 + lane];
#pragma unroll
      for (int i = 0; i < 4; ++i)
        acc[i] = __builtin_amdgcn_mfma_f32_16x16x32_bf16(ah, whfS[i][kt], acc[i], 0, 0, 0);
    }

    if (t > 0) {
      // staging waves: poll peer's h_{t-1} half DIRECTLY on the data
      // (poison 0xFFFFFFFF = bf16 NaN pair, unreachable for sigm*tanh).
      if (tid < 256) {
        int m = tid >> 4, seg = tid & 15;
        const unsigned* src = reinterpret_cast<const unsigned*>(
            hs + ((long)(t - 1) * B_SZ + b0 + m) * H_SZ + peer * 128 + seg * 8);
        unsigned d0, d1, d2, d3;
        do {
          d0 = __hip_atomic_load(src + 0, __ATOMIC_RELAXED, __HIP_MEMORY_SCOPE_AGENT);
          d1 = __hip_atomic_load(src + 1, __ATOMIC_RELAXED, __HIP_MEMORY_SCOPE_AGENT);
          d2 = __hip_atomic_load(src + 2, __ATOMIC_RELAXED, __HIP_MEMORY_SCOPE_AGENT);
          d3 = __hip_atomic_load(src + 3, __ATOMIC_RELAXED, __HIP_MEMORY_SCOPE_AGENT);
        } while (d0 == HPOISON || d1 == HPOISON || d2 == HPOISON || d3 == HPOISON);
        union { unsigned u[4]; short8 s; } cv;
        cv.u[0] = d0; cv.u[1] = d1; cv.u[2] = d2; cv.u[3] = d3;
        // 16B read lands exactly on one A-frag: kt = peer*4 + (seg>>2),
        // lane = (seg&3)*16 + m
        hsh[cur][(peer * 4 + (seg >> 2)) * 64 + (seg & 3) * 16 + m] = cv.s;
      }
      __syncthreads();  // syncB
    }
    // peer-half h recurrence
#pragma unroll
    for (int kt = 0; kt < 4; ++kt) {
      short8 ah = hsh[cur][(peer * 4 + kt) * 64 + lane];
#pragma unroll
      for (int i = 0; i < 4; ++i)
        acc[i] = __builtin_amdgcn_mfma_f32_16x16x32_bf16(ah, whfP[i][kt], acc[i], 0, 0, 0);
    }

    // elementwise, fully in-register: lane owns (m = quad*4+r, hu) for r=0..3
    bf16* hbn = reinterpret_cast<bf16*>(&hsh[nxt][0]);
    unsigned hpk[4];
#pragma unroll
    for (int r = 0; r < 4; ++r) {
      float iv = sigm(acc[0][r] + bia[0]);
      float fv = sigm(acc[1][r] + bia[1]);
      float gv = ftanh(acc[2][r] + bia[2]);
      float ov = sigm(acc[3][r] + bia[3]);
      c[r] = fv * c[r] + iv * gv;
      bf16 hv = f2bf(ov * ftanh(c[r]));
      int m = quad * 4 + r;
      // local scatter into next step's A-frag buffer (LDS)
      hbn[(((hu >> 5) * 64) + ((hu >> 3) & 3) * 16 + m) * 8 + (hu & 7)] = hv;
      // pack (hu, hu+1) into a dword for the MALL publish (even l15 lanes)
      unsigned hraw = (unsigned)*reinterpret_cast<unsigned short*>(&hv);
      unsigned nb = (unsigned)__shfl_down((int)hraw, 1, 64);
      hpk[r] = hraw | (nb << 16);
    }
    if (dopre) xsh[nxt][tid] = xpre;  // land the x prefetch
    __syncthreads();  // syncD (fences LDS for next step; drains prior VMEM)
    // publish h_t AFTER the barrier: off the critical path, retires under
    // next step's compute. Peer polls the data itself.
    if ((l15 & 1) == 0) {
#pragma unroll
      for (int r = 0; r < 4; ++r) {
        int m = quad * 4 + r;
        unsigned* dst = reinterpret_cast<unsigned*>(
            hs + ((long)t * B_SZ + b0 + m) * H_SZ + hu);
        __hip_atomic_store(dst, hpk[r], __ATOMIC_RELAXED,
                           __HIP_MEMORY_SCOPE_AGENT);
      }
    }
  }
}

// ---------------------------------------------------------------------------
// 3) TPA stage A (r8-tuned, kept): u = hn @ W_tpa; w2 = W_conv^T u; c0.
// ---------------------------------------------------------------------------
__global__ __launch_bounds__(256) void k_u(
    const bf16* __restrict__ hs, const bf16* __restrict__ W_tpa,
    const bf16* __restrict__ W_conv, const bf16* __restrict__ b_conv,
    float* __restrict__ w2, float* __restrict__ c0) {
  __shared__ float hn_sh[8][256];
  __shared__ float u_sh[8][256];
  __shared__ float wred[4][8];
  int tid = threadIdx.x;
  long b0 = (long)blockIdx.x * 8;
#pragma unroll
  for (int r = 0; r < 8; r++)
    hn_sh[r][tid] = bf2f(hs[((long)(T_SZ - 1) * B_SZ + b0 + r) * H_SZ + tid]);
  __syncthreads();
  float u[8] = {0,0,0,0,0,0,0,0};
  for (int kk = 0; kk < 32; kk++) {
    float wv[8];
#pragma unroll
    for (int q = 0; q < 8; q++)
      wv[q] = bf2f(W_tpa[(kk * 8 + q) * H_SZ + tid]);
#pragma unroll
    for (int r = 0; r < 8; r++) {
      const float4* hp = reinterpret_cast<const float4*>(&hn_sh[r][kk * 8]);
      float4 h0 = hp[0], h1 = hp[1];
      u[r] += h0.x * wv[0]; u[r] += h0.y * wv[1];
      u[r] += h0.z * wv[2]; u[r] += h0.w * wv[3];
      u[r] += h1.x * wv[4]; u[r] += h1.y * wv[5];
      u[r] += h1.z * wv[6]; u[r] += h1.w * wv[7];
    }
  }
  float bc = bf2f(b_conv[tid]);
  float p[8];
#pragma unroll
  for (int r = 0; r < 8; r++) { u_sh[r][tid] = u[r]; p[r] = u[r] * bc; }
#pragma unroll
  for (int d = 32; d > 0; d >>= 1)
#pragma unroll
    for (int r = 0; r < 8; r++) p[r] += __shfl_down(p[r], d, 64);
  if ((tid & 63) == 0)
#pragma unroll
    for (int r = 0; r < 8; r++) wred[tid >> 6][r] = p[r];
  __syncthreads();
  if (tid < 8)
    c0[b0 + tid] = wred[0][tid] + wred[1][tid] + wred[2][tid] + wred[3][tid];
  if (tid < T_SZ) {
    float a[8] = {0,0,0,0,0,0,0,0};
    for (int jj = 0; jj < 32; jj++) {
      float wv[8];
#pragma unroll
      for (int q = 0; q < 8; q++)
        wv[q] = bf2f(W_conv[(jj * 8 + q) * T_SZ + tid]);
#pragma unroll
      for (int r = 0; r < 8; r++) {
        const float4* up = reinterpret_cast<const float4*>(&u_sh[r][jj * 8]);
        float4 u0 = up[0], u1 = up[1];
        a[r] += u0.x * wv[0]; a[r] += u0.y * wv[1];
        a[r] += u0.z * wv[2]; a[r] += u0.w * wv[3];
        a[r] += u1.x * wv[4]; a[r] += u1.y * wv[5];
        a[r] += u1.z * wv[6]; a[r] += u1.w * wv[7];
      }
    }
#pragma unroll
    for (int r = 0; r < 8; r++) w2[(b0 + r) * T_SZ + tid] = a[r];
  }
}

// ---------------------------------------------------------------------------
// 4) Fused alpha+s (r8-measured, kept): one block per b; hs slice in LDS.
// ---------------------------------------------------------------------------
__global__ __launch_bounds__(256) void k_alphas(
    const bf16* __restrict__ hs, const float* __restrict__ w2,
    const float* __restrict__ c0, float* __restrict__ asum,
    float* __restrict__ sbuf) {
  __shared__ unsigned hc[128 * 129];  // 66KB; row t at hc[t*129], 128 words
  __shared__ float w2s[T_SZ];
  __shared__ float ash[H_SZ];
  __shared__ float red[256];
  int b = blockIdx.x, tid = threadIdx.x;
#pragma unroll
  for (int p = 0; p < 16; p++) {
    int task = p * 256 + tid;
    int row = task >> 5, seg = task & 31;
    short8 v = *reinterpret_cast<const short8*>(
        hs + ((long)row * B_SZ + b) * H_SZ + seg * 8);
    union { short8 s; unsigned u[4]; } cv; cv.s = v;
#pragma unroll
    for (int k = 0; k < 4; k++) hc[row * 129 + seg * 4 + k] = cv.u[k];
  }
  if (tid < T_SZ) w2s[tid] = w2[b * T_SZ + tid];
  __syncthreads();
  {
    float ap = c0[b];
    int wi = tid >> 1, hi = tid & 1;
    for (int t = 0; t < T_SZ; t++) {
      unsigned uv = hc[t * 129 + wi];
      unsigned short h16 = hi ? (unsigned short)(uv >> 16) : (unsigned short)(uv & 0xFFFF);
      float hvf = __bfloat162float(*reinterpret_cast<bf16*>(&h16));
      ap += hvf * w2s[t];
    }
    float a = sigm(ap);
    ash[tid] = a;
    red[tid] = a;
  }
  __syncthreads();
  for (int s = 128; s > 0; s >>= 1) {
    if (tid < s) red[tid] += red[tid + s];
    __syncthreads();
  }
  if (tid == 0) asum[b] = red[0];
  if (tid < T_SZ) {
    float acc = 0.f;
    for (int k = 0; k < 128; k++) {
      int wi = (k + tid) & 127;
      unsigned uv = hc[tid * 129 + wi];
      unsigned short lo16 = (unsigned short)(uv & 0xFFFF);
      unsigned short hi16 = (unsigned short)(uv >> 16);
      float lo = __bfloat162float(*reinterpret_cast<bf16*>(&lo16));
      float hi = __bfloat162float(*reinterpret_cast<bf16*>(&hi16));
      acc += ash[2 * wi] * lo + ash[2 * wi + 1] * hi;
    }
    sbuf[b * T_SZ + tid] = acc;
  }
}

// ---------------------------------------------------------------------------
// 5) k_finmlp — round-9 fusion (kept verbatim): k_fin + k_mlp in one kernel;
//    fin lives in LDS a_sh[pos*8+r]; fin round-trip + a launch eliminated.
// ---------------------------------------------------------------------------
__global__ __launch_bounds__(512) void k_finmlp(
    const bf16* __restrict__ hs, const float* __restrict__ sbuf,
    const float* __restrict__ asum, const bf16* __restrict__ WcvT,
    const bf16* __restrict__ b_conv, const bf16* __restrict__ WthT,
    const bf16* __restrict__ WtcT, const bf16* __restrict__ WltT,
    const bf16* __restrict__ b_ltd, const int* __restrict__ ns_cat,
    const bf16* __restrict__ emb_ns0, const bf16* __restrict__ emb_ns1,
    const bf16* __restrict__ ns_cont, const bf16* __restrict__ W_f1,
    const bf16* __restrict__ b_f1, const bf16* __restrict__ g1,
    const bf16* __restrict__ be1, const bf16* __restrict__ m1,
    const bf16* __restrict__ v1, const bf16* __restrict__ W_f2,
    const bf16* __restrict__ b_f2, const bf16* __restrict__ g2,
    const bf16* __restrict__ be2, const bf16* __restrict__ m2,
    const bf16* __restrict__ v2, const bf16* __restrict__ W_out,
    const bf16* __restrict__ b_out, void* __restrict__ d_out_raw,
    const unsigned* __restrict__ probe) {
  bool isf32 = ((probe[0] & 0xFFFFu) == 0u);
  __shared__ float s_sh[8][128];      // 4KB
  __shared__ float hn_sh[8][256];     // 8KB
  __shared__ float vt_sh[8][256];     // 8KB
  __shared__ float a_sh[FINW * 8];    // 21.5KB: fin, transposed a_sh[pos*8+r]
  __shared__ float x1t[512 * 8];      // 16KB
  __shared__ float x2t[256 * 8];      // 8KB   -> total ~65.5KB
  int tid = threadIdx.x;
  int h = tid & 255, rh = tid >> 8;   // this thread owns rows r = rh*4..rh*4+3
  long b0 = (long)blockIdx.x * 8;
  auto store2 = [&](int r, int pos, float v) {
    a_sh[pos * 8 + r] = v;
    if (isf32)
      ((float*)d_out_raw + 65536)[(b0 + r) * FINW + pos] = v;
    else
      ((bf16*)d_out_raw + 65536)[(b0 + r) * FINW + pos] = f2bf(v);
  };
  if (tid < 128)
#pragma unroll
    for (int r = 0; r < 8; r++) s_sh[r][tid] = sbuf[(b0 + r) * T_SZ + tid];
#pragma unroll
  for (int rr = 0; rr < 4; rr++) {
    int r = rh * 4 + rr;
    hn_sh[r][h] = bf2f(hs[((long)(T_SZ - 1) * B_SZ + b0 + r) * H_SZ + h]);
  }
  __syncthreads();
  float vt[4] = {0, 0, 0, 0};
  for (int tt = 0; tt < 16; tt++) {
    float wv[8];
#pragma unroll
    for (int q = 0; q < 8; q++)
      wv[q] = bf2f(WcvT[(tt * 8 + q) * H_SZ + h]);
#pragma unroll
    for (int rr = 0; rr < 4; rr++) {
      int r = rh * 4 + rr;
      const float4* sp = reinterpret_cast<const float4*>(&s_sh[r][tt * 8]);
      float4 s0 = sp[0], s1 = sp[1];
      vt[rr] += wv[0] * s0.x; vt[rr] += wv[1] * s0.y;
      vt[rr] += wv[2] * s0.z; vt[rr] += wv[3] * s0.w;
      vt[rr] += wv[4] * s1.x; vt[rr] += wv[5] * s1.y;
      vt[rr] += wv[6] * s1.z; vt[rr] += wv[7] * s1.w;
    }
  }
  float bc = bf2f(b_conv[h]);
#pragma unroll
  for (int rr = 0; rr < 4; rr++) {
    int r = rh * 4 + rr;
    vt[rr] += bc * asum[b0 + r];
    vt_sh[r][h] = vt[rr];
  }
  __syncthreads();
  float htp[4] = {0, 0, 0, 0}, sq[4] = {0, 0, 0, 0};
  for (int kk = 0; kk < 32; kk++) {
    float wh[8], wc[8], wl[8];
#pragma unroll
    for (int q = 0; q < 8; q++) {
      int k = kk * 8 + q;
      wh[q] = bf2f(WthT[k * H_SZ + h]);
      wc[q] = bf2f(WtcT[k * H_SZ + h]);
      wl[q] = bf2f(WltT[k * H_SZ + h]);
    }
#pragma unroll
    for (int rr = 0; rr < 4; rr++) {
      int r = rh * 4 + rr;
      const float4* hp = reinterpret_cast<const float4*>(&hn_sh[r][kk * 8]);
      const float4* vp = reinterpret_cast<const float4*>(&vt_sh[r][kk * 8]);
      float4 h0 = hp[0], h1 = hp[1], v0 = vp[0], v1 = vp[1];
      htp[rr] += h0.x * wh[0] + v0.x * wc[0]; sq[rr] += h0.x * wl[0];
      htp[rr] += h0.y * wh[1] + v0.y * wc[1]; sq[rr] += h0.y * wl[1];
      htp[rr] += h0.z * wh[2] + v0.z * wc[2]; sq[rr] += h0.z * wl[2];
      htp[rr] += h0.w * wh[3] + v0.w * wc[3]; sq[rr] += h0.w * wl[3];
      htp[rr] += h1.x * wh[4] + v1.x * wc[4]; sq[rr] += h1.x * wl[4];
      htp[rr] += h1.y * wh[5] + v1.y * wc[5]; sq[rr] += h1.y * wl[5];
      htp[rr] += h1.z * wh[6] + v1.z * wc[6]; sq[rr] += h1.z * wl[6];
      htp[rr] += h1.w * wh[7] + v1.w * wc[7]; sq[rr] += h1.w * wl[7];
    }
  }
  float bl = bf2f(b_ltd[h]);
#pragma unroll
  for (int rr = 0; rr < 4; rr++) {
    int r = rh * 4 + rr;
    store2(r, 160 + h, sq[rr] + bl);
    store2(r, 416 + h, htp[rr]);
  }
  if (tid < 160) {
#pragma unroll
    for (int r = 0; r < 8; r++) {
      long b = b0 + r;
      float v;
      if (tid < 64)       v = bf2f(emb_ns0[(long)ns_cat[b * 2 + 0] * 64 + tid]);
      else if (tid < 128) v = bf2f(emb_ns1[(long)ns_cat[b * 2 + 1] * 64 + tid - 64]);
      else                v = bf2f(ns_cont[b * 32 + tid - 128]);
      store2(r, tid, v);
    }
  }
  __syncthreads();
  // ================= MLP phase (round-8 k_mlp) =================
  {  // layer 1: n = tid (512 outputs), k = 672 = 168*4
    int n = tid;
    float acc[8] = {0, 0, 0, 0, 0, 0, 0, 0};
    const short4v* wr4 = reinterpret_cast<const short4v*>(W_f1 + (long)n * FINW);
    for (int kk = 0; kk < FINW / 4; kk++) {
      short4v w4 = wr4[kk];
#pragma unroll
      for (int j = 0; j < 4; j++) {
        float wv = bfraw2f((unsigned short)w4[j]);
        const float4* ap = reinterpret_cast<const float4*>(&a_sh[(kk * 4 + j) * 8]);
        float4 a0 = ap[0], a1 = ap[1];
        acc[0] += wv * a0.x; acc[1] += wv * a0.y;
        acc[2] += wv * a0.z; acc[3] += wv * a0.w;
        acc[4] += wv * a1.x; acc[5] += wv * a1.y;
        acc[6] += wv * a1.z; acc[7] += wv * a1.w;
      }
    }
    float bb = bf2f(b_f1[n]);
    float scale = bf2f(g1[n]) * rsqrtf(bf2f(v1[n]) + 1e-5f);
    float mm = bf2f(m1[n]), bee = bf2f(be1[n]);
#pragma unroll
    for (int r = 0; r < 8; r++) {
      float x = acc[r] + bb;
      x = x > 0.f ? x : 0.f;
      x1t[n * 8 + r] = (x - mm) * scale + bee;
    }
  }
  __syncthreads();
  if (tid < 256) {  // layer 2: n = tid (256 outputs), k = 512 = 64*8
    int n = tid;
    float acc[8] = {0, 0, 0, 0, 0, 0, 0, 0};
    const short8* wr8 = reinterpret_cast<const short8*>(W_f2 + (long)n * 512);
    for (int kk = 0; kk < 64; kk++) {
      short8 w8 = wr8[kk];
#pragma unroll
      for (int j = 0; j < 8; j++) {
        float wv = bfraw2f((unsigned short)w8[j]);
        const float4* ap = reinterpret_cast<const float4*>(&x1t[(kk * 8 + j) * 8]);
        float4 a0 = ap[0], a1 = ap[1];
        acc[0] += wv * a0.x; acc[1] += wv * a0.y;
        acc[2] += wv * a0.z; acc[3] += wv * a0.w;
        acc[4] += wv * a1.x; acc[5] += wv * a1.y;
        acc[6] += wv * a1.z; acc[7] += wv * a1.w;
      }
    }
    float bb = bf2f(b_f2[n]);
    float scale = bf2f(g2[n]) * rsqrtf(bf2f(v2[n]) + 1e-5f);
    float mm = bf2f(m2[n]), bee = bf2f(be2[n]);
#pragma unroll
    for (int r = 0; r < 8; r++) {
      float x = acc[r] + bb;
      x = x > 0.f ? x : 0.f;
      x2t[n * 8 + r] = (x - mm) * scale + bee;
    }
  }
  __syncthreads();
  if (tid < 64) {  // layer 3: n = tid (64 outputs), k = 256 = 32*8
    int n = tid;
    float acc[8] = {0, 0, 0, 0, 0, 0, 0, 0};
    const short8* wr8 = reinterpret_cast<const short8*>(W_out + (long)n * H_SZ);
    for (int kk = 0; kk < 32; kk++) {
      short8 w8 = wr8[kk];
#pragma unroll
      for (int j = 0; j < 8; j++) {
        float wv = bfraw2f((unsigned short)w8[j]);
        const float4* ap = reinterpret_cast<const float4*>(&x2t[(kk * 8 + j) * 8]);
        float4 a0 = ap[0], a1 = ap[1];
        acc[0] += wv * a0.x; acc[1] += wv * a0.y;
        acc[2] += wv * a0.z; acc[3] += wv * a0.w;
        acc[4] += wv * a1.x; acc[5] += wv * a1.y;
        acc[6] += wv * a1.z; acc[7] += wv * a1.w;
      }
    }
    float bb = bf2f(b_out[n]);
#pragma unroll
    for (int r = 0; r < 8; r++) {
      float x = acc[r] + bb;
      x = x > 0.f ? x : 0.f;
      if (isf32)
        ((float*)d_out_raw)[(b0 + r) * 64 + n] = x;
      else
        ((bf16*)d_out_raw)[(b0 + r) * 64 + n] = f2bf(x);
    }
  }
}

// ---------------------------------------------------------------------------
extern "C" void kernel_launch(void* const* d_in, const int* in_sizes, int n_in,
                              void* d_out, int out_size, void* d_ws,
                              size_t ws_size, hipStream_t stream) {
  const int* seq_cat = (const int*)d_in[1];
  const int* ns_cat  = (const int*)d_in[2];
  const unsigned* probe = (const unsigned*)d_in[24];  // v1 = ones

  // workspace layout — total ~102MB (fin eliminated; seqd reinstated)
  char* ws = (char*)d_ws;
  bf16* seqd  = (bf16*)ws;  ws += (size_t)T_SZ * B_SZ * DIN * 2;   // 32MB
  bf16* hsb   = (bf16*)ws;  ws += (size_t)T_SZ * B_SZ * H_SZ * 2;  // 64MB
  bf16* arena = (bf16*)ws;  ws += (size_t)ARENA_TOTAL2 * 2;        // ~4.4MB
  float* w2   = (float*)ws; ws += (size_t)B_SZ * T_SZ * 4;
  float* c0   = (float*)ws; ws += (size_t)B_SZ * 4;
  float* asum = (float*)ws; ws += (size_t)B_SZ * 4;
  float* sbuf = (float*)ws; ws += (size_t)B_SZ * T_SZ * 4;

  const bf16* c_ns_cont = arena + 0;
  const bf16* c_emb_ns0 = arena + 32768;
  const bf16* c_emb_ns1 = arena + 672768;
  const bf16* c_emb_s0  = arena + 736768;
  const bf16* c_emb_s1  = arena + 768768;
  const bf16* c_W_ih    = arena + 784768;
  const bf16* c_W_hh    = arena + 915840;
  const bf16* c_b_ih    = arena + 1177984;
  const bf16* c_b_hh    = arena + 1179008;
  const bf16* c_b_ltd   = arena + 1245568;
  const bf16* c_W_conv  = arena + 1245824;
  const bf16* c_b_conv  = arena + 1278592;
  const bf16* c_W_tpa   = arena + 1278848;
  const bf16* c_W_f1    = arena + 1475456;
  const bf16* c_b_f1    = arena + 1819520;
  const bf16* c_g1      = arena + 1820032;
  const bf16* c_be1     = arena + 1820544;
  const bf16* c_m1      = arena + 1821056;
  const bf16* c_v1      = arena + 1821568;
  const bf16* c_W_f2    = arena + 1822080;
  const bf16* c_b_f2    = arena + 1953152;
  const bf16* c_g2      = arena + 1953408;
  const bf16* c_be2     = arena + 1953664;
  const bf16* c_m2      = arena + 1953920;
  const bf16* c_v2      = arena + 1954176;
  const bf16* c_W_out   = arena + 1954432;
  const bf16* c_b_out   = arena + 1970816;
  const bf16* c_WthT    = arena + TR_BASE + TR_WthT;
  const bf16* c_WtcT    = arena + TR_BASE + TR_WtcT;
  const bf16* c_WltT    = arena + TR_BASE + TR_WltT;
  const bf16* c_WcvT    = arena + TR_BASE + TR_WcvT;

  Ptrs pk;
  for (int i = 0; i < 33; i++) pk.p[i] = d_in[i];

  // k_convert also poisons hs (data-is-flag sentinel; hs write-once/cell)
  k_convert<<<dim3(512), 256, 0, stream>>>(pk, arena, (uint4*)hsb);
  k_gather<<<dim3(B_SZ * T_SZ * 16 / 256), 256, 0, stream>>>(
      d_in[0], seq_cat, c_emb_s0, c_emb_s1, seqd, probe);
  k_lstm<<<dim3(128), 512, 0, stream>>>(seqd, c_W_ih, c_W_hh, c_b_ih, c_b_hh,
                                        hsb);
  k_u<<<dim3(B_SZ / 8), 256, 0, stream>>>(hsb, c_W_tpa, c_W_conv, c_b_conv, w2, c0);
  k_alphas<<<dim3(B_SZ), 256, 0, stream>>>(hsb, w2, c0, asum, sbuf);
  k_finmlp<<<dim3(B_SZ / 8), 512, 0, stream>>>(
      hsb, sbuf, asum, c_WcvT, c_b_conv, c_WthT, c_WtcT, c_WltT, c_b_ltd,
      ns_cat, c_emb_ns0, c_emb_ns1, c_ns_cont, c_W_f1, c_b_f1, c_g1, c_be1,
      c_m1, c_v1, c_W_f2, c_b_f2, c_g2, c_be2, c_m2, c_v2, c_W_out, c_b_out,
      d_out, probe);
}

// Round 13
// 626.506 us; speedup vs baseline: 1.1305x; 1.0164x over previous
//
#include <hip/hip_runtime.h>
#include <hip/hip_bf16.h>
#include <math.h>

// Problem constants
#define B_SZ 1024
#define T_SZ 128
#define H_SZ 256
#define DIN  128
#define G4   1024   // 4*H
#define FINW 672

using bf16   = __hip_bfloat16;
using short8 = __attribute__((ext_vector_type(8))) short;  // 8 bf16 (4 VGPRs)
using short4v = __attribute__((ext_vector_type(4))) short;
using f32x4  = __attribute__((ext_vector_type(4))) float;

__device__ __forceinline__ float bf2f(bf16 x) { return __bfloat162float(x); }
__device__ __forceinline__ bf16  f2bf(float x) { return __float2bfloat16(x); }
__device__ __forceinline__ float sigm(float x) { return 1.0f / (1.0f + __expf(-x)); }
__device__ __forceinline__ float ftanh(float x) { return 2.0f / (1.0f + __expf(-2.0f * x)) - 1.0f; }
__device__ __forceinline__ float bfraw2f(unsigned short r) {
  unsigned u = ((unsigned)r) << 16;
  return *reinterpret_cast<float*>(&u);
}

struct Ptrs { const void* p[33]; };

#define NSEG 30
__device__ __host__ constexpr int kSegOffArr(int i) {
  constexpr int off[NSEG + 1] = {
      0,       32768,   672768,  736768,  768768,  784768,  915840,
      1177984, 1179008, 1180032, 1245568, 1245824, 1278592, 1278848,
      1344384, 1409920, 1475456, 1819520, 1820032, 1820544, 1821056,
      1821568, 1822080, 1953152, 1953408, 1953664, 1953920, 1954176,
      1954432, 1970816, 1970880};
  return off[i];
}
#define ARENA_TOTAL 1970880
// transposed-weight extension region: WT[k][n] layouts for k_finmlp
#define TR_BASE   1970880
#define TR_WthT   0        // 65536  (W_tpa_h^T, src p[17])
#define TR_WtcT   65536    // 65536  (W_tpa_c^T, src p[18])
#define TR_WltT   131072   // 65536  (W_ltd^T,   src p[12])
#define TR_WcvT   196608   // 32768  (W_conv^T,  src p[14])
#define TR_TOTAL  229376
#define ARENA_TOTAL2 (ARENA_TOTAL + TR_TOTAL)

// ---------------------------------------------------------------------------
// 0) k_prep — merge of k_convert + k_gather (+ hs poison):
//    blocks [0,1024): arena convert + transposed weights + hs poison;
//    blocks [1024,3072): seq gather reading RAW inputs (emb converted
//    inline with the same f2bf -> bit-identical to the arena path).
//    The two halves are data-independent -> run concurrently in one launch.
// ---------------------------------------------------------------------------
#define PREP_CONV_BLOCKS 1024
#define PREP_TOTAL_BLOCKS 3072
__global__ __launch_bounds__(256) void k_prep(
    Ptrs pk, bf16* __restrict__ dst, uint4* __restrict__ hsp,
    const int* __restrict__ seq_cat, bf16* __restrict__ seq_out) {
  bool isf32 = ((((const unsigned*)pk.p[24])[0] & 0xFFFFu) == 0u);
  int bid = blockIdx.x;
  if (bid < PREP_CONV_BLOCKS) {
    int stride = PREP_CONV_BLOCKS * 256;
    int gtid = bid * 256 + threadIdx.x;
    for (int i = gtid; i < ARENA_TOTAL; i += stride) {
      int s = 0, base = 0;
#pragma unroll
      for (int j = 1; j < NSEG; j++) {
        bool ge = (i >= kSegOffArr(j));
        s    = ge ? j : s;
        base = ge ? kSegOffArr(j) : base;
      }
      int off = i - base;
      const void* src = pk.p[3 + s];
      dst[i] = isf32 ? f2bf(((const float*)src)[off]) : ((const bf16*)src)[off];
    }
    // transposed copies: WT[k*N + n] = W[n*K + k]
    for (int j = gtid; j < TR_TOTAL; j += stride) {
      const void* src;
      int off;
      if (j < TR_WtcT)      { src = pk.p[17]; int jj = j;            off = (jj & 255) * 256 + (jj >> 8); }
      else if (j < TR_WltT) { src = pk.p[18]; int jj = j - TR_WtcT;  off = (jj & 255) * 256 + (jj >> 8); }
      else if (j < TR_WcvT) { src = pk.p[12]; int jj = j - TR_WltT;  off = (jj & 255) * 256 + (jj >> 8); }
      else                  { src = pk.p[14]; int jj = j - TR_WcvT;  off = (jj & 255) * 128 + (jj >> 8); }
      dst[TR_BASE + j] = isf32 ? f2bf(((const float*)src)[off]) : ((const bf16*)src)[off];
    }
    // hs poison: 0xFFFFFFFF (bf16 NaN pair) data-is-flag sentinel. 64MB.
    uint4 pv = make_uint4(0xFFFFFFFFu, 0xFFFFFFFFu, 0xFFFFFFFFu, 0xFFFFFFFFu);
    for (int i = gtid; i < (int)((size_t)T_SZ * B_SZ * H_SZ * 2 / 16); i += stride)
      hsp[i] = pv;
  } else {
    // gather: seq_out[t*B + b][0:128] = [emb_s0(32) | emb_s1(32) | cont(64)]
    const void* cont_raw = pk.p[0];
    const void* e0raw = pk.p[6];
    const void* e1raw = pk.p[7];
    int stride = (PREP_TOTAL_BLOCKS - PREP_CONV_BLOCKS) * 256;
    for (int task = (bid - PREP_CONV_BLOCKS) * 256 + (int)threadIdx.x;
         task < B_SZ * T_SZ * 16; task += stride) {
      int seg = task & 15;
      int m   = task >> 4;       // m = t*B + b
      int t   = m >> 10;
      int b   = m & 1023;
      bf16* dstp = seq_out + (long)m * DIN + seg * 8;
      if (seg < 8) {
        const void* eraw;
        long eoff;
        if (seg < 4) {
          int idx = seq_cat[(b * T_SZ + t) * 2 + 0];
          eraw = e0raw; eoff = (long)idx * 32 + seg * 8;
        } else {
          int idx = seq_cat[(b * T_SZ + t) * 2 + 1];
          eraw = e1raw; eoff = (long)idx * 32 + (seg - 4) * 8;
        }
        if (isf32) {
          const float4* sp = reinterpret_cast<const float4*>((const float*)eraw + eoff);
          float4 x0 = sp[0], x1 = sp[1];
          union { short8 v; bf16 h[8]; } u;
          u.h[0] = f2bf(x0.x); u.h[1] = f2bf(x0.y); u.h[2] = f2bf(x0.z); u.h[3] = f2bf(x0.w);
          u.h[4] = f2bf(x1.x); u.h[5] = f2bf(x1.y); u.h[6] = f2bf(x1.z); u.h[7] = f2bf(x1.w);
          *reinterpret_cast<short8*>(dstp) = u.v;
        } else {
          *reinterpret_cast<short8*>(dstp) =
              *reinterpret_cast<const short8*>((const bf16*)eraw + eoff);
        }
      } else {
        long base = ((long)b * T_SZ + t) * 64 + (seg - 8) * 8;
        if (isf32) {
          const float4* sp =
              reinterpret_cast<const float4*>((const float*)cont_raw + base);
          float4 x0 = sp[0], x1 = sp[1];
          union { short8 v; bf16 h[8]; } u;
          u.h[0] = f2bf(x0.x); u.h[1] = f2bf(x0.y); u.h[2] = f2bf(x0.z); u.h[3] = f2bf(x0.w);
          u.h[4] = f2bf(x1.x); u.h[5] = f2bf(x1.y); u.h[6] = f2bf(x1.z); u.h[7] = f2bf(x1.w);
          *reinterpret_cast<short8*>(dstp) = u.v;
        } else {
          *reinterpret_cast<short8*>(dstp) =
              *reinterpret_cast<const short8*>((const bf16*)cont_raw + base);
        }
      }
    }
  }
}

// ---------------------------------------------------------------------------
// 2) LSTM — EXACT round-3/round-8 kernel (best measured: 353-361us).
//    Frozen: lgkm-only barriers regressed (r7), L2 exchange refuted (r5/r6),
//    inline gather regressed (r9/r10). At the T*lambda MALL-exchange floor.
// ---------------------------------------------------------------------------
#define HPOISON 0xFFFFFFFFu
__global__ __launch_bounds__(512, 2) void k_lstm(
    const bf16* __restrict__ seq, const bf16* __restrict__ Wih,
    const bf16* __restrict__ Whh, const bf16* __restrict__ bih,
    const bf16* __restrict__ bhh, bf16* __restrict__ hs) {
  __shared__ short8 hsh[2][8 * 64];   // 16KB: h_{t-1} A-frags, double-buffered
  __shared__ short8 xsh[2][4 * 64];   // 8KB:  x_t A-frags, double-buffered
  int tid  = threadIdx.x;
  int w    = tid >> 6, lane = tid & 63;
  int quad = lane >> 4, l15 = lane & 15;
  int bid  = blockIdx.x;
  int gid  = bid & 63;   // group (16 batch rows)
  int rank = bid >> 6;   // 0..1 (owns h-units [rank*128, +128))
  int peer = 1 - rank;
  long b0  = (long)gid * 16;
  int hup = w * 16 + l15;        // rank-local h-unit this lane owns (0..127)
  int hu  = rank * 128 + hup;    // global h-unit (0..255)

  { short8 z = {0,0,0,0,0,0,0,0}; hsh[0][tid] = z; }  // h_{-1} = 0 (both halves)

  // per-lane bias for this lane's 4 gates of h-unit hu
  float bia[4];
#pragma unroll
  for (int i = 0; i < 4; ++i) {
    int grow = i * H_SZ + hu;
    bia[i] = bf2f(bih[grow]) + bf2f(bhh[grow]);
  }

  // resident weights: gate i rows i*H + rank*128 + hup. All indices
  // compile-time (full unroll) -> registers/AGPRs (r8 verified).
  short8 wif[4][4];    // Wih  frags
  short8 whfS[4][4];   // Whh, self-half kts
  short8 whfP[4][4];   // Whh, peer-half kts
#pragma unroll
  for (int i = 0; i < 4; ++i) {
    long grow = (long)(i * H_SZ + rank * 128 + hup);
#pragma unroll
    for (int kt = 0; kt < 4; ++kt) {
      wif[i][kt] = *reinterpret_cast<const short8*>(
          Wih + grow * DIN + kt * 32 + quad * 8);
      whfS[i][kt] = *reinterpret_cast<const short8*>(
          Whh + grow * H_SZ + (rank * 4 + kt) * 32 + quad * 8);
      whfP[i][kt] = *reinterpret_cast<const short8*>(
          Whh + grow * H_SZ + (peer * 4 + kt) * 32 + quad * 8);
    }
  }
  // prologue: stage x_0
  if (tid < 256)
    xsh[0][tid] = *reinterpret_cast<const short8*>(
        seq + (b0 + (tid & 15)) * DIN + (tid >> 6) * 32 +
        ((tid >> 4) & 3) * 8);
  float c[4] = {0.f, 0.f, 0.f, 0.f};
  __syncthreads();

  for (int t = 0; t < T_SZ; ++t) {
    int cur = t & 1, nxt = cur ^ 1;
    // issue x_{t+1} prefetch into regs (ds_write'd at end of step)
    short8 xpre;
    bool dopre = (t + 1 < T_SZ) & (tid < 256);
    if (dopre)
      xpre = *reinterpret_cast<const short8*>(
          seq + ((long)(t + 1) * B_SZ + b0 + (tid & 15)) * DIN +
          (tid >> 6) * 32 + ((tid >> 4) & 3) * 8);

    f32x4 acc[4];
#pragma unroll
    for (int i = 0; i < 4; ++i) acc[i] = {0.f, 0.f, 0.f, 0.f};

    // x-projection (resident wif)
#pragma unroll
    for (int kt = 0; kt < 4; ++kt) {
      short8 ax = xsh[cur][kt * 64 + lane];
#pragma unroll
      for (int i = 0; i < 4; ++i)
        acc[i] = __builtin_amdgcn_mfma_f32_16x16x32_bf16(ax, wif[i][kt], acc[i], 0, 0, 0);
    }
    // self-half h recurrence (scattered locally last step via LDS)
#pragma unroll
    for (int kt = 0; kt < 4; ++kt) {
      short8 ah = hsh[cur][(rank * 4 + kt) * 64 + lane];
#pragma unroll
      for (int i = 0; i < 4; ++i)
        acc[i] = __builtin_amdgcn_mfma_f32_16x16x32_bf16(ah, whfS[i][kt], acc[i], 0, 0, 0);
    }

    if (t > 0) {
      // staging waves: poll peer's h_{t-1} half DIRECTLY on the data
      // (poison 0xFFFFFFFF = bf16 NaN pair, unreachable for sigm*tanh).
      if (tid < 256) {
        int m = tid >> 4, seg = tid & 15;
        const unsigned* src = reinterpret_cast<const unsigned*>(
            hs + ((long)(t - 1) * B_SZ + b0 + m) * H_SZ + peer * 128 + seg * 8);
        unsigned d0, d1, d2, d3;
        do {
          d0 = __hip_atomic_load(src + 0, __ATOMIC_RELAXED, __HIP_MEMORY_SCOPE_AGENT);
          d1 = __hip_atomic_load(src + 1, __ATOMIC_RELAXED, __HIP_MEMORY_SCOPE_AGENT);
          d2 = __hip_atomic_load(src + 2, __ATOMIC_RELAXED, __HIP_MEMORY_SCOPE_AGENT);
          d3 = __hip_atomic_load(src + 3, __ATOMIC_RELAXED, __HIP_MEMORY_SCOPE_AGENT);
        } while (d0 == HPOISON || d1 == HPOISON || d2 == HPOISON || d3 == HPOISON);
        union { unsigned u[4]; short8 s; } cv;
        cv.u[0] = d0; cv.u[1] = d1; cv.u[2] = d2; cv.u[3] = d3;
        // 16B read lands exactly on one A-frag: kt = peer*4 + (seg>>2),
        // lane = (seg&3)*16 + m
        hsh[cur][(peer * 4 + (seg >> 2)) * 64 + (seg & 3) * 16 + m] = cv.s;
      }
      __syncthreads();  // syncB
    }
    // peer-half h recurrence
#pragma unroll
    for (int kt = 0; kt < 4; ++kt) {
      short8 ah = hsh[cur][(peer * 4 + kt) * 64 + lane];
#pragma unroll
      for (int i = 0; i < 4; ++i)
        acc[i] = __builtin_amdgcn_mfma_f32_16x16x32_bf16(ah, whfP[i][kt], acc[i], 0, 0, 0);
    }

    // elementwise, fully in-register: lane owns (m = quad*4+r, hu) for r=0..3
    bf16* hbn = reinterpret_cast<bf16*>(&hsh[nxt][0]);
    unsigned hpk[4];
#pragma unroll
    for (int r = 0; r < 4; ++r) {
      float iv = sigm(acc[0][r] + bia[0]);
      float fv = sigm(acc[1][r] + bia[1]);
      float gv = ftanh(acc[2][r] + bia[2]);
      float ov = sigm(acc[3][r] + bia[3]);
      c[r] = fv * c[r] + iv * gv;
      bf16 hv = f2bf(ov * ftanh(c[r]));
      int m = quad * 4 + r;
      // local scatter into next step's A-frag buffer (LDS)
      hbn[(((hu >> 5) * 64) + ((hu >> 3) & 3) * 16 + m) * 8 + (hu & 7)] = hv;
      // pack (hu, hu+1) into a dword for the MALL publish (even l15 lanes)
      unsigned hraw = (unsigned)*reinterpret_cast<unsigned short*>(&hv);
      unsigned nb = (unsigned)__shfl_down((int)hraw, 1, 64);
      hpk[r] = hraw | (nb << 16);
    }
    if (dopre) xsh[nxt][tid] = xpre;  // land the x prefetch
    __syncthreads();  // syncD (fences LDS for next step; drains prior VMEM)
    // publish h_t AFTER the barrier: off the critical path, retires under
    // next step's compute. Peer polls the data itself.
    if ((l15 & 1) == 0) {
#pragma unroll
      for (int r = 0; r < 4; ++r) {
        int m = quad * 4 + r;
        unsigned* dst = reinterpret_cast<unsigned*>(
            hs + ((long)t * B_SZ + b0 + m) * H_SZ + hu);
        __hip_atomic_store(dst, hpk[r], __ATOMIC_RELAXED,
                           __HIP_MEMORY_SCOPE_AGENT);
      }
    }
  }
}

// ---------------------------------------------------------------------------
// 4) k_ualphas — fusion of k_u into k_alphas. One block per b: stage hn + hc;
//    compute u (identical 8-wide k loop), c0 (identical shfl tree +
//    wred[0..3] sum order), w2 (identical jj loop) LOCALLY; then the r8
//    alpha+s body reading w2s/c0 from LDS. Numerics bit-identical.
// ---------------------------------------------------------------------------
__global__ __launch_bounds__(256) void k_ualphas(
    const bf16* __restrict__ hs, const bf16* __restrict__ W_tpa,
    const bf16* __restrict__ W_conv, const bf16* __restrict__ b_conv,
    float* __restrict__ asum, float* __restrict__ sbuf) {
  __shared__ unsigned hc[128 * 129];  // 66KB; row t at hc[t*129], 128 words
  __shared__ float hn_sh[256];
  __shared__ float u_sh[256];
  __shared__ float w2s[T_SZ];
  __shared__ float ash[H_SZ];
  __shared__ float red[256];
  __shared__ float wred[4];
  int b = blockIdx.x, tid = threadIdx.x;
#pragma unroll
  for (int p = 0; p < 16; p++) {
    int task = p * 256 + tid;
    int row = task >> 5, seg = task & 31;
    short8 v = *reinterpret_cast<const short8*>(
        hs + ((long)row * B_SZ + b) * H_SZ + seg * 8);
    union { short8 s; unsigned u[4]; } cv; cv.s = v;
#pragma unroll
    for (int k = 0; k < 4; k++) hc[row * 129 + seg * 4 + k] = cv.u[k];
  }
  hn_sh[tid] = bf2f(hs[((long)(T_SZ - 1) * B_SZ + b) * H_SZ + tid]);
  __syncthreads();
  // u[tid] = sum_k hn[k] * W_tpa[k*H + tid]  (identical order to k_u)
  float u = 0.f;
  for (int kk = 0; kk < 32; kk++) {
    float wv[8];
#pragma unroll
    for (int q = 0; q < 8; q++)
      wv[q] = bf2f(W_tpa[(kk * 8 + q) * H_SZ + tid]);
    const float4* hp = reinterpret_cast<const float4*>(&hn_sh[kk * 8]);
    float4 h0 = hp[0], h1 = hp[1];
    u += h0.x * wv[0]; u += h0.y * wv[1];
    u += h0.z * wv[2]; u += h0.w * wv[3];
    u += h1.x * wv[4]; u += h1.y * wv[5];
    u += h1.z * wv[6]; u += h1.w * wv[7];
  }
  u_sh[tid] = u;
  // c0 = dot(u, b_conv): identical shfl tree + wred order as k_u
  float p = u * bf2f(b_conv[tid]);
#pragma unroll
  for (int d = 32; d > 0; d >>= 1) p += __shfl_down(p, d, 64);
  if ((tid & 63) == 0) wred[tid >> 6] = p;
  __syncthreads();
  // w2[t] = sum_j u[j] * W_conv[j*T + t]  (identical order to k_u)
  if (tid < T_SZ) {
    float a = 0.f;
    for (int jj = 0; jj < 32; jj++) {
      float wv[8];
#pragma unroll
      for (int q = 0; q < 8; q++)
        wv[q] = bf2f(W_conv[(jj * 8 + q) * T_SZ + tid]);
      const float4* up = reinterpret_cast<const float4*>(&u_sh[jj * 8]);
      float4 u0 = up[0], u1 = up[1];
      a += u0.x * wv[0]; a += u0.y * wv[1];
      a += u0.z * wv[2]; a += u0.w * wv[3];
      a += u1.x * wv[4]; a += u1.y * wv[5];
      a += u1.z * wv[6]; a += u1.w * wv[7];
    }
    w2s[tid] = a;
  }
  __syncthreads();
  {
    // ap base = wred[0]+wred[1]+wred[2]+wred[3] (same order as k_u's c0)
    float ap = wred[0] + wred[1] + wred[2] + wred[3];
    int wi = tid >> 1, hi = tid & 1;
    for (int t = 0; t < T_SZ; t++) {
      unsigned uv = hc[t * 129 + wi];
      unsigned short h16 = hi ? (unsigned short)(uv >> 16) : (unsigned short)(uv & 0xFFFF);
      float hvf = __bfloat162float(*reinterpret_cast<bf16*>(&h16));
      ap += hvf * w2s[t];
    }
    float a = sigm(ap);
    ash[tid] = a;
    red[tid] = a;
  }
  __syncthreads();
  for (int s = 128; s > 0; s >>= 1) {
    if (tid < s) red[tid] += red[tid + s];
    __syncthreads();
  }
  if (tid == 0) asum[b] = red[0];
  if (tid < T_SZ) {
    float acc = 0.f;
    for (int k = 0; k < 128; k++) {
      int wi = (k + tid) & 127;
      unsigned uv = hc[tid * 129 + wi];
      unsigned short lo16 = (unsigned short)(uv & 0xFFFF);
      unsigned short hi16 = (unsigned short)(uv >> 16);
      float lo = __bfloat162float(*reinterpret_cast<bf16*>(&lo16));
      float hi = __bfloat162float(*reinterpret_cast<bf16*>(&hi16));
      acc += ash[2 * wi] * lo + ash[2 * wi + 1] * hi;
    }
    sbuf[b * T_SZ + tid] = acc;
  }
}

// ---------------------------------------------------------------------------
// 5) k_finmlp — round-9 fusion (kept verbatim): k_fin + k_mlp in one kernel;
//    fin lives in LDS a_sh[pos*8+r]; fin round-trip + a launch eliminated.
// ---------------------------------------------------------------------------
__global__ __launch_bounds__(512) void k_finmlp(
    const bf16* __restrict__ hs, const float* __restrict__ sbuf,
    const float* __restrict__ asum, const bf16* __restrict__ WcvT,
    const bf16* __restrict__ b_conv, const bf16* __restrict__ WthT,
    const bf16* __restrict__ WtcT, const bf16* __restrict__ WltT,
    const bf16* __restrict__ b_ltd, const int* __restrict__ ns_cat,
    const bf16* __restrict__ emb_ns0, const bf16* __restrict__ emb_ns1,
    const bf16* __restrict__ ns_cont, const bf16* __restrict__ W_f1,
    const bf16* __restrict__ b_f1, const bf16* __restrict__ g1,
    const bf16* __restrict__ be1, const bf16* __restrict__ m1,
    const bf16* __restrict__ v1, const bf16* __restrict__ W_f2,
    const bf16* __restrict__ b_f2, const bf16* __restrict__ g2,
    const bf16* __restrict__ be2, const bf16* __restrict__ m2,
    const bf16* __restrict__ v2, const bf16* __restrict__ W_out,
    const bf16* __restrict__ b_out, void* __restrict__ d_out_raw,
    const unsigned* __restrict__ probe) {
  bool isf32 = ((probe[0] & 0xFFFFu) == 0u);
  __shared__ float s_sh[8][128];      // 4KB
  __shared__ float hn_sh[8][256];     // 8KB
  __shared__ float vt_sh[8][256];     // 8KB
  __shared__ float a_sh[FINW * 8];    // 21.5KB: fin, transposed a_sh[pos*8+r]
  __shared__ float x1t[512 * 8];      // 16KB
  __shared__ float x2t[256 * 8];      // 8KB   -> total ~65.5KB
  int tid = threadIdx.x;
  int h = tid & 255, rh = tid >> 8;   // this thread owns rows r = rh*4..rh*4+3
  long b0 = (long)blockIdx.x * 8;
  auto store2 = [&](int r, int pos, float v) {
    a_sh[pos * 8 + r] = v;
    if (isf32)
      ((float*)d_out_raw + 65536)[(b0 + r) * FINW + pos] = v;
    else
      ((bf16*)d_out_raw + 65536)[(b0 + r) * FINW + pos] = f2bf(v);
  };
  if (tid < 128)
#pragma unroll
    for (int r = 0; r < 8; r++) s_sh[r][tid] = sbuf[(b0 + r) * T_SZ + tid];
#pragma unroll
  for (int rr = 0; rr < 4; rr++) {
    int r = rh * 4 + rr;
    hn_sh[r][h] = bf2f(hs[((long)(T_SZ - 1) * B_SZ + b0 + r) * H_SZ + h]);
  }
  __syncthreads();
  float vt[4] = {0, 0, 0, 0};
  for (int tt = 0; tt < 16; tt++) {
    float wv[8];
#pragma unroll
    for (int q = 0; q < 8; q++)
      wv[q] = bf2f(WcvT[(tt * 8 + q) * H_SZ + h]);
#pragma unroll
    for (int rr = 0; rr < 4; rr++) {
      int r = rh * 4 + rr;
      const float4* sp = reinterpret_cast<const float4*>(&s_sh[r][tt * 8]);
      float4 s0 = sp[0], s1 = sp[1];
      vt[rr] += wv[0] * s0.x; vt[rr] += wv[1] * s0.y;
      vt[rr] += wv[2] * s0.z; vt[rr] += wv[3] * s0.w;
      vt[rr] += wv[4] * s1.x; vt[rr] += wv[5] * s1.y;
      vt[rr] += wv[6] * s1.z; vt[rr] += wv[7] * s1.w;
    }
  }
  float bc = bf2f(b_conv[h]);
#pragma unroll
  for (int rr = 0; rr < 4; rr++) {
    int r = rh * 4 + rr;
    vt[rr] += bc * asum[b0 + r];
    vt_sh[r][h] = vt[rr];
  }
  __syncthreads();
  float htp[4] = {0, 0, 0, 0}, sq[4] = {0, 0, 0, 0};
  for (int kk = 0; kk < 32; kk++) {
    float wh[8], wc[8], wl[8];
#pragma unroll
    for (int q = 0; q < 8; q++) {
      int k = kk * 8 + q;
      wh[q] = bf2f(WthT[k * H_SZ + h]);
      wc[q] = bf2f(WtcT[k * H_SZ + h]);
      wl[q] = bf2f(WltT[k * H_SZ + h]);
    }
#pragma unroll
    for (int rr = 0; rr < 4; rr++) {
      int r = rh * 4 + rr;
      const float4* hp = reinterpret_cast<const float4*>(&hn_sh[r][kk * 8]);
      const float4* vp = reinterpret_cast<const float4*>(&vt_sh[r][kk * 8]);
      float4 h0 = hp[0], h1 = hp[1], v0 = vp[0], v1 = vp[1];
      htp[rr] += h0.x * wh[0] + v0.x * wc[0]; sq[rr] += h0.x * wl[0];
      htp[rr] += h0.y * wh[1] + v0.y * wc[1]; sq[rr] += h0.y * wl[1];
      htp[rr] += h0.z * wh[2] + v0.z * wc[2]; sq[rr] += h0.z * wl[2];
      htp[rr] += h0.w * wh[3] + v0.w * wc[3]; sq[rr] += h0.w * wl[3];
      htp[rr] += h1.x * wh[4] + v1.x * wc[4]; sq[rr] += h1.x * wl[4];
      htp[rr] += h1.y * wh[5] + v1.y * wc[5]; sq[rr] += h1.y * wl[5];
      htp[rr] += h1.z * wh[6] + v1.z * wc[6]; sq[rr] += h1.z * wl[6];
      htp[rr] += h1.w * wh[7] + v1.w * wc[7]; sq[rr] += h1.w * wl[7];
    }
  }
  float bl = bf2f(b_ltd[h]);
#pragma unroll
  for (int rr = 0; rr < 4; rr++) {
    int r = rh * 4 + rr;
    store2(r, 160 + h, sq[rr] + bl);
    store2(r, 416 + h, htp[rr]);
  }
  if (tid < 160) {
#pragma unroll
    for (int r = 0; r < 8; r++) {
      long b = b0 + r;
      float v;
      if (tid < 64)       v = bf2f(emb_ns0[(long)ns_cat[b * 2 + 0] * 64 + tid]);
      else if (tid < 128) v = bf2f(emb_ns1[(long)ns_cat[b * 2 + 1] * 64 + tid - 64]);
      else                v = bf2f(ns_cont[b * 32 + tid - 128]);
      store2(r, tid, v);
    }
  }
  __syncthreads();
  // ================= MLP phase (round-8 k_mlp) =================
  {  // layer 1: n = tid (512 outputs), k = 672 = 168*4
    int n = tid;
    float acc[8] = {0, 0, 0, 0, 0, 0, 0, 0};
    const short4v* wr4 = reinterpret_cast<const short4v*>(W_f1 + (long)n * FINW);
    for (int kk = 0; kk < FINW / 4; kk++) {
      short4v w4 = wr4[kk];
#pragma unroll
      for (int j = 0; j < 4; j++) {
        float wv = bfraw2f((unsigned short)w4[j]);
        const float4* ap = reinterpret_cast<const float4*>(&a_sh[(kk * 4 + j) * 8]);
        float4 a0 = ap[0], a1 = ap[1];
        acc[0] += wv * a0.x; acc[1] += wv * a0.y;
        acc[2] += wv * a0.z; acc[3] += wv * a0.w;
        acc[4] += wv * a1.x; acc[5] += wv * a1.y;
        acc[6] += wv * a1.z; acc[7] += wv * a1.w;
      }
    }
    float bb = bf2f(b_f1[n]);
    float scale = bf2f(g1[n]) * rsqrtf(bf2f(v1[n]) + 1e-5f);
    float mm = bf2f(m1[n]), bee = bf2f(be1[n]);
#pragma unroll
    for (int r = 0; r < 8; r++) {
      float x = acc[r] + bb;
      x = x > 0.f ? x : 0.f;
      x1t[n * 8 + r] = (x - mm) * scale + bee;
    }
  }
  __syncthreads();
  if (tid < 256) {  // layer 2: n = tid (256 outputs), k = 512 = 64*8
    int n = tid;
    float acc[8] = {0, 0, 0, 0, 0, 0, 0, 0};
    const short8* wr8 = reinterpret_cast<const short8*>(W_f2 + (long)n * 512);
    for (int kk = 0; kk < 64; kk++) {
      short8 w8 = wr8[kk];
#pragma unroll
      for (int j = 0; j < 8; j++) {
        float wv = bfraw2f((unsigned short)w8[j]);
        const float4* ap = reinterpret_cast<const float4*>(&x1t[(kk * 8 + j) * 8]);
        float4 a0 = ap[0], a1 = ap[1];
        acc[0] += wv * a0.x; acc[1] += wv * a0.y;
        acc[2] += wv * a0.z; acc[3] += wv * a0.w;
        acc[4] += wv * a1.x; acc[5] += wv * a1.y;
        acc[6] += wv * a1.z; acc[7] += wv * a1.w;
      }
    }
    float bb = bf2f(b_f2[n]);
    float scale = bf2f(g2[n]) * rsqrtf(bf2f(v2[n]) + 1e-5f);
    float mm = bf2f(m2[n]), bee = bf2f(be2[n]);
#pragma unroll
    for (int r = 0; r < 8; r++) {
      float x = acc[r] + bb;
      x = x > 0.f ? x : 0.f;
      x2t[n * 8 + r] = (x - mm) * scale + bee;
    }
  }
  __syncthreads();
  if (tid < 64) {  // layer 3: n = tid (64 outputs), k = 256 = 32*8
    int n = tid;
    float acc[8] = {0, 0, 0, 0, 0, 0, 0, 0};
    const short8* wr8 = reinterpret_cast<const short8*>(W_out + (long)n * H_SZ);
    for (int kk = 0; kk < 32; kk++) {
      short8 w8 = wr8[kk];
#pragma unroll
      for (int j = 0; j < 8; j++) {
        float wv = bfraw2f((unsigned short)w8[j]);
        const float4* ap = reinterpret_cast<const float4*>(&x2t[(kk * 8 + j) * 8]);
        float4 a0 = ap[0], a1 = ap[1];
        acc[0] += wv * a0.x; acc[1] += wv * a0.y;
        acc[2] += wv * a0.z; acc[3] += wv * a0.w;
        acc[4] += wv * a1.x; acc[5] += wv * a1.y;
        acc[6] += wv * a1.z; acc[7] += wv * a1.w;
      }
    }
    float bb = bf2f(b_out[n]);
#pragma unroll
    for (int r = 0; r < 8; r++) {
      float x = acc[r] + bb;
      x = x > 0.f ? x : 0.f;
      if (isf32)
        ((float*)d_out_raw)[(b0 + r) * 64 + n] = x;
      else
        ((bf16*)d_out_raw)[(b0 + r) * 64 + n] = f2bf(x);
    }
  }
}

// ---------------------------------------------------------------------------
extern "C" void kernel_launch(void* const* d_in, const int* in_sizes, int n_in,
                              void* d_out, int out_size, void* d_ws,
                              size_t ws_size, hipStream_t stream) {
  const int* seq_cat = (const int*)d_in[1];
  const int* ns_cat  = (const int*)d_in[2];
  const unsigned* probe = (const unsigned*)d_in[24];  // v1 = ones

  // workspace layout — total ~101MB
  char* ws = (char*)d_ws;
  bf16* seqd  = (bf16*)ws;  ws += (size_t)T_SZ * B_SZ * DIN * 2;   // 32MB
  bf16* hsb   = (bf16*)ws;  ws += (size_t)T_SZ * B_SZ * H_SZ * 2;  // 64MB
  bf16* arena = (bf16*)ws;  ws += (size_t)ARENA_TOTAL2 * 2;        // ~4.4MB
  float* asum = (float*)ws; ws += (size_t)B_SZ * 4;
  float* sbuf = (float*)ws; ws += (size_t)B_SZ * T_SZ * 4;

  const bf16* c_ns_cont = arena + 0;
  const bf16* c_emb_ns0 = arena + 32768;
  const bf16* c_emb_ns1 = arena + 672768;
  const bf16* c_W_ih    = arena + 784768;
  const bf16* c_W_hh    = arena + 915840;
  const bf16* c_b_ih    = arena + 1177984;
  const bf16* c_b_hh    = arena + 1179008;
  const bf16* c_b_ltd   = arena + 1245568;
  const bf16* c_W_conv  = arena + 1245824;
  const bf16* c_b_conv  = arena + 1278592;
  const bf16* c_W_tpa   = arena + 1278848;
  const bf16* c_W_f1    = arena + 1475456;
  const bf16* c_b_f1    = arena + 1819520;
  const bf16* c_g1      = arena + 1820032;
  const bf16* c_be1     = arena + 1820544;
  const bf16* c_m1      = arena + 1821056;
  const bf16* c_v1      = arena + 1821568;
  const bf16* c_W_f2    = arena + 1822080;
  const bf16* c_b_f2    = arena + 1953152;
  const bf16* c_g2      = arena + 1953408;
  const bf16* c_be2     = arena + 1953664;
  const bf16* c_m2      = arena + 1953920;
  const bf16* c_v2      = arena + 1954176;
  const bf16* c_W_out   = arena + 1954432;
  const bf16* c_b_out   = arena + 1970816;
  const bf16* c_WthT    = arena + TR_BASE + TR_WthT;
  const bf16* c_WtcT    = arena + TR_BASE + TR_WtcT;
  const bf16* c_WltT    = arena + TR_BASE + TR_WltT;
  const bf16* c_WcvT    = arena + TR_BASE + TR_WcvT;

  Ptrs pk;
  for (int i = 0; i < 33; i++) pk.p[i] = d_in[i];

  // one prep launch: convert + transposed weights + hs poison + gather
  k_prep<<<dim3(PREP_TOTAL_BLOCKS), 256, 0, stream>>>(pk, arena, (uint4*)hsb,
                                                      seq_cat, seqd);
  k_lstm<<<dim3(128), 512, 0, stream>>>(seqd, c_W_ih, c_W_hh, c_b_ih, c_b_hh,
                                        hsb);
  k_ualphas<<<dim3(B_SZ), 256, 0, stream>>>(hsb, c_W_tpa, c_W_conv, c_b_conv,
                                            asum, sbuf);
  k_finmlp<<<dim3(B_SZ / 8), 512, 0, stream>>>(
      hsb, sbuf, asum, c_WcvT, c_b_conv, c_WthT, c_WtcT, c_WltT, c_b_ltd,
      ns_cat, c_emb_ns0, c_emb_ns1, c_ns_cont, c_W_f1, c_b_f1, c_g1, c_be1,
      c_m1, c_v1, c_W_f2, c_b_f2, c_g2, c_be2, c_m2, c_v2, c_W_out, c_b_out,
      d_out, probe);
}